// Round 2
// baseline (1958.985 us; speedup 1.0000x reference)
//
#include <hip/hip_runtime.h>
#include <hip/hip_bf16.h>
#include <stdint.h>

#define NN 100000
#define NE 1600000
#define FIN 128
#define HID 64
#define COUT 16

typedef unsigned long long u64;

struct Flags { int f32; int i64; };

__device__ __forceinline__ float b2f(__hip_bfloat16 v) { return __bfloat162float(v); }

// adaptive float load: fp32 buffer or bf16 buffer
__device__ __forceinline__ float ldf(const void* p, size_t i, int f32) {
    return f32 ? ((const float*)p)[i]
               : __bfloat162float(((const __hip_bfloat16*)p)[i]);
}
// adaptive edge-index load: int32 or int64 buffer, logical index i in [0, 2*NE)
__device__ __forceinline__ int lde(const void* p, size_t i, int i64) {
    return i64 ? (int)((const long long*)p)[i] : ((const int*)p)[i];
}

// ---- K0: detect input dtypes on-device (same work every call; deterministic) ----
__global__ void k_detect(const unsigned short* xs, const int* ei32, Flags* fl) {
    if (threadIdx.x == 0 && blockIdx.x == 0) {
        // If x is fp32, even-indexed 16-bit words are low mantissa halves:
        // uniform-random exponent field -> some word has exponent >= 0xC0.
        // If x is bf16 (N(0,1) values), exponent <= 0x81 always.
        int huge = 0;
        for (int i = 0; i < 1024; i += 2) {
            int e = (xs[i] >> 7) & 0xFF;
            if (e >= 0xC0) huge = 1;
        }
        // If edge_index is int64 (node ids < 2^31), odd int32 words are all 0.
        // If int32, odd words are random node ids (P(zero) = 1e-5 each).
        int odd_nonzero = 0;
        for (int i = 1; i < 512; i += 2)
            if (ei32[i] != 0) odd_nonzero = 1;
        fl->f32 = huge;
        fl->i64 = !odd_nonzero;
    }
}

// ---- K1: degree (segment_sum of ew over col) + argmin over edges with row==0 ----
__global__ void k_deg_min(const void* __restrict__ ei, const void* __restrict__ ew,
                          const Flags* __restrict__ fl,
                          float* __restrict__ deg, u64* __restrict__ minkey) {
    int e = blockIdx.x * blockDim.x + threadIdx.x;
    if (e >= NE) return;
    int f32 = fl->f32, i64 = fl->i64;
    int r = lde(ei, e, i64);
    int c = lde(ei, (size_t)NE + e, i64);
    float w = ldf(ew, e, f32);
    atomicAdd(&deg[c], w);
    if (r == 0) {
        // w >= 0 so float bits are monotone; low 32 bits break ties to lowest index
        u64 key = ((u64)__float_as_uint(w) << 32) | (unsigned)e;
        atomicMin(minkey, key);
    }
}

// ---- K2: dinv for both layers ----
__global__ void k_dinv(const float* __restrict__ deg, const void* __restrict__ ei,
                       const void* __restrict__ ew, const Flags* __restrict__ fl,
                       const u64* __restrict__ minkey,
                       float* __restrict__ dinv1, float* __restrict__ dinv2) {
    int i = blockIdx.x * blockDim.x + threadIdx.x;
    if (i >= NN) return;
    int f32 = fl->f32, i64 = fl->i64;
    u64 k = *minkey;
    int eidx = (k == ~0ull) ? 0 : (int)(k & 0xffffffffu);  // argmin(all-inf)==0, like jnp
    int cmin = lde(ei, (size_t)NE + eidx, i64);
    float wmin = ldf(ew, eidx, f32);
    float d1 = deg[i] + 1.0f;                 // +1 for self loop
    float d2 = d1 - ((i == cmin) ? wmin : 0.0f);
    dinv1[i] = rsqrtf(d1);
    dinv2[i] = rsqrtf(d2);
}

// ---- K3: h1 = x @ W1  (100000x128 @ 128x64, fp32 accumulate) ----
__global__ __launch_bounds__(256) void k_gemm1(const void* __restrict__ x,
                                               const void* __restrict__ W1,
                                               const Flags* __restrict__ fl,
                                               float* __restrict__ h1) {
    __shared__ float Ws[FIN * HID];  // 32 KB
    int t = threadIdx.x;
    int f32 = fl->f32;
    for (int i = t; i < FIN * HID; i += 256) Ws[i] = ldf(W1, i, f32);
    __syncthreads();
    int node = blockIdx.x * 16 + (t >> 4);  // 16 nodes/block, 16 threads/node
    if (node >= NN) return;
    int o4 = (t & 15) * 4;                  // 4 outputs/thread
    float a0 = 0.f, a1 = 0.f, a2 = 0.f, a3 = 0.f;
    if (f32) {
        const float* xr = (const float*)x + (size_t)node * FIN;
#pragma unroll 4
        for (int k = 0; k < FIN; ++k) {
            float xv = xr[k];
            const float* wr = &Ws[k * HID + o4];
            a0 += xv * wr[0]; a1 += xv * wr[1]; a2 += xv * wr[2]; a3 += xv * wr[3];
        }
    } else {
        const __hip_bfloat16* xr = (const __hip_bfloat16*)x + (size_t)node * FIN;
#pragma unroll 4
        for (int k = 0; k < FIN; ++k) {
            float xv = b2f(xr[k]);
            const float* wr = &Ws[k * HID + o4];
            a0 += xv * wr[0]; a1 += xv * wr[1]; a2 += xv * wr[2]; a3 += xv * wr[3];
        }
    }
    float* ho = h1 + (size_t)node * HID + o4;
    ho[0] = a0; ho[1] = a1; ho[2] = a2; ho[3] = a3;
}

// ---- K4: agg1[col] += norm1(e) * h1[row]  (16 threads/edge, float4 each) ----
__global__ void k_scatter1(const void* __restrict__ ei, const void* __restrict__ ew,
                           const Flags* __restrict__ fl,
                           const float* __restrict__ dinv1, const float* __restrict__ h1,
                           float* __restrict__ agg1) {
    long long tid = (long long)blockIdx.x * blockDim.x + threadIdx.x;
    int e = (int)(tid >> 4);
    if (e >= NE) return;
    int f32 = fl->f32, i64 = fl->i64;
    int f = ((int)tid & 15) * 4;
    int r = lde(ei, e, i64);
    int c = lde(ei, (size_t)NE + e, i64);
    float nw = dinv1[r] * ldf(ew, e, f32) * dinv1[c];
    const float4 hv = *(const float4*)(h1 + (size_t)r * HID + f);
    float* dst = agg1 + (size_t)c * HID + f;
    atomicAdd(dst + 0, nw * hv.x);
    atomicAdd(dst + 1, nw * hv.y);
    atomicAdd(dst + 2, nw * hv.z);
    atomicAdd(dst + 3, nw * hv.w);
}

// ---- K5: out1 = relu(agg1 + dinv1^2 * h1 + b1), in place in agg1 ----
__global__ void k_epi1(float* __restrict__ agg1, const float* __restrict__ h1,
                       const float* __restrict__ dinv1, const void* __restrict__ b1,
                       const Flags* __restrict__ fl) {
    int tid = blockIdx.x * blockDim.x + threadIdx.x;  // NN*16 float4 units
    if (tid >= NN * 16) return;
    int f32 = fl->f32;
    int n = tid >> 4;
    int f = (tid & 15) * 4;
    float s = dinv1[n]; s = s * s;
    size_t idx = (size_t)n * HID + f;
    float4 a = *(float4*)(agg1 + idx);
    float4 h = *(const float4*)(h1 + idx);
    a.x = fmaxf(a.x + s * h.x + ldf(b1, f + 0, f32), 0.f);
    a.y = fmaxf(a.y + s * h.y + ldf(b1, f + 1, f32), 0.f);
    a.z = fmaxf(a.z + s * h.z + ldf(b1, f + 2, f32), 0.f);
    a.w = fmaxf(a.w + s * h.w + ldf(b1, f + 3, f32), 0.f);
    *(float4*)(agg1 + idx) = a;
}

// ---- K6: h2 = out1 @ W2  (100000x64 @ 64x16) ----
__global__ __launch_bounds__(256) void k_gemm2(const float* __restrict__ out1,
                                               const void* __restrict__ W2,
                                               const Flags* __restrict__ fl,
                                               float* __restrict__ h2) {
    __shared__ float Ws[HID * COUT];  // 4 KB
    int t = threadIdx.x;
    int f32 = fl->f32;
    for (int i = t; i < HID * COUT; i += 256) Ws[i] = ldf(W2, i, f32);
    __syncthreads();
    int node = blockIdx.x * 64 + (t >> 2);  // 64 nodes/block, 4 threads/node
    if (node >= NN) return;
    int o4 = (t & 3) * 4;
    const float* xr = out1 + (size_t)node * HID;
    float a0 = 0.f, a1 = 0.f, a2 = 0.f, a3 = 0.f;
#pragma unroll 4
    for (int k = 0; k < HID; ++k) {
        float xv = xr[k];
        const float* wr = &Ws[k * COUT + o4];
        a0 += xv * wr[0]; a1 += xv * wr[1]; a2 += xv * wr[2]; a3 += xv * wr[3];
    }
    float* ho = h2 + (size_t)node * COUT + o4;
    ho[0] = a0; ho[1] = a1; ho[2] = a2; ho[3] = a3;
}

// ---- K7: agg2[col] += norm2(e) * h2[row]  (4 threads/edge, float4 each) ----
__global__ void k_scatter2(const void* __restrict__ ei, const void* __restrict__ ew,
                           const Flags* __restrict__ fl, const u64* __restrict__ minkey,
                           const float* __restrict__ dinv2, const float* __restrict__ h2,
                           float* __restrict__ agg2) {
    long long tid = (long long)blockIdx.x * blockDim.x + threadIdx.x;
    int e = (int)(tid >> 2);
    if (e >= NE) return;
    int f32 = fl->f32, i64 = fl->i64;
    int f = ((int)tid & 3) * 4;
    u64 k = *minkey;
    int eidx = (k == ~0ull) ? 0 : (int)(k & 0xffffffffu);
    int r = lde(ei, e, i64);
    int c = lde(ei, (size_t)NE + e, i64);
    float w = (e == eidx) ? 0.0f : ldf(ew, e, f32);
    float nw = dinv2[r] * w * dinv2[c];
    const float4 hv = *(const float4*)(h2 + (size_t)r * COUT + f);
    float* dst = agg2 + (size_t)c * COUT + f;
    atomicAdd(dst + 0, nw * hv.x);
    atomicAdd(dst + 1, nw * hv.y);
    atomicAdd(dst + 2, nw * hv.z);
    atomicAdd(dst + 3, nw * hv.w);
}

// ---- K8: out = agg2 + dinv2^2 * h2 + b2  -> fp32 or bf16 per flag ----
__global__ void k_epi2(const float* __restrict__ agg2, const float* __restrict__ h2,
                       const float* __restrict__ dinv2, const void* __restrict__ bias2,
                       const Flags* __restrict__ fl, void* __restrict__ out) {
    int tid = blockIdx.x * blockDim.x + threadIdx.x;  // NN*4 float4 units
    if (tid >= NN * 4) return;
    int f32 = fl->f32;
    int n = tid >> 2;
    int f = (tid & 3) * 4;
    float s = dinv2[n]; s = s * s;
    size_t idx = (size_t)n * COUT + f;
    float4 a = *(const float4*)(agg2 + idx);
    float4 h = *(const float4*)(h2 + idx);
    float o0 = a.x + s * h.x + ldf(bias2, f + 0, f32);
    float o1 = a.y + s * h.y + ldf(bias2, f + 1, f32);
    float o2 = a.z + s * h.z + ldf(bias2, f + 2, f32);
    float o3 = a.w + s * h.w + ldf(bias2, f + 3, f32);
    if (f32) {
        float* op = (float*)out + idx;
        op[0] = o0; op[1] = o1; op[2] = o2; op[3] = o3;
    } else {
        __hip_bfloat16* op = (__hip_bfloat16*)out + idx;
        op[0] = __float2bfloat16(o0); op[1] = __float2bfloat16(o1);
        op[2] = __float2bfloat16(o2); op[3] = __float2bfloat16(o3);
    }
}

extern "C" void kernel_launch(void* const* d_in, const int* in_sizes, int n_in,
                              void* d_out, int out_size, void* d_ws, size_t ws_size,
                              hipStream_t stream) {
    const void* x  = d_in[0];
    const void* ei = d_in[1];
    const void* ew = d_in[2];
    const void* W1 = d_in[3];
    const void* b1 = d_in[4];
    const void* W2 = d_in[5];
    const void* b2 = d_in[6];

    // workspace layout (fp32): 16.3M floats + 16 bytes = ~65.2 MB
    float* ws    = (float*)d_ws;
    float* deg   = ws;                       // NN
    float* dinv1 = deg + NN;                 // NN
    float* dinv2 = dinv1 + NN;               // NN
    float* h1    = dinv2 + NN;               // NN*HID
    float* agg1  = h1 + (size_t)NN * HID;    // NN*HID (becomes out1 after epi1)
    float* h2    = agg1 + (size_t)NN * HID;  // NN*COUT
    float* agg2  = h2 + (size_t)NN * COUT;   // NN*COUT
    u64*   minkey = (u64*)(agg2 + (size_t)NN * COUT);  // 8 B (8-aligned)
    Flags* fl    = (Flags*)(minkey + 1);     // 8 B

    // zero-init accumulators (ws is poisoned 0xAA before every call)
    hipMemsetAsync(deg,  0, (size_t)NN * sizeof(float), stream);
    hipMemsetAsync(agg1, 0, (size_t)NN * HID * sizeof(float), stream);
    hipMemsetAsync(agg2, 0, (size_t)NN * COUT * sizeof(float), stream);
    hipMemsetAsync(minkey, 0xFF, sizeof(u64), stream);

    k_detect<<<1, 64, 0, stream>>>((const unsigned short*)x, (const int*)ei, fl);
    k_deg_min<<<(NE + 255) / 256, 256, 0, stream>>>(ei, ew, fl, deg, minkey);
    k_dinv<<<(NN + 255) / 256, 256, 0, stream>>>(deg, ei, ew, fl, minkey, dinv1, dinv2);
    k_gemm1<<<(NN + 15) / 16, 256, 0, stream>>>(x, W1, fl, h1);
    k_scatter1<<<(int)(((long long)NE * 16 + 255) / 256), 256, 0, stream>>>(ei, ew, fl, dinv1, h1, agg1);
    k_epi1<<<(NN * 16 + 255) / 256, 256, 0, stream>>>(agg1, h1, dinv1, b1, fl);
    k_gemm2<<<(NN + 63) / 64, 256, 0, stream>>>(agg1, W2, fl, h2);
    k_scatter2<<<(int)(((long long)NE * 4 + 255) / 256), 256, 0, stream>>>(ei, ew, fl, minkey, dinv2, h2, agg2);
    k_epi2<<<(NN * 4 + 255) / 256, 256, 0, stream>>>(agg2, h2, dinv2, b2, fl, d_out);
}

// Round 3
// 799.799 us; speedup vs baseline: 2.4493x; 2.4493x over previous
//
#include <hip/hip_runtime.h>
#include <hip/hip_bf16.h>
#include <stdint.h>

#define NN 100000
#define NE 1600000
#define FIN 128
#define HID 64
#define COUT 16

typedef unsigned long long u64;

struct Flags { int f32; int i64; };

__device__ __forceinline__ float b2f(__hip_bfloat16 v) { return __bfloat162float(v); }

// adaptive float load: fp32 buffer or bf16 buffer
__device__ __forceinline__ float ldf(const void* p, size_t i, int f32) {
    return f32 ? ((const float*)p)[i]
               : __bfloat162float(((const __hip_bfloat16*)p)[i]);
}
// adaptive edge-index load: int32 or int64 buffer, logical index i in [0, 2*NE)
__device__ __forceinline__ int lde(const void* p, size_t i, int i64) {
    return i64 ? (int)((const long long*)p)[i] : ((const int*)p)[i];
}
// load 4 consecutive bf16 (8B-aligned) -> 4 floats
__device__ __forceinline__ void ld4bf(const __hip_bfloat16* p, float& x0, float& x1,
                                      float& x2, float& x3) {
    union { uint2 u; __hip_bfloat16 h[4]; } v;
    v.u = *(const uint2*)p;
    x0 = b2f(v.h[0]); x1 = b2f(v.h[1]); x2 = b2f(v.h[2]); x3 = b2f(v.h[3]);
}

// ---- K0: detect input dtypes on-device (same work every call; deterministic) ----
__global__ void k_detect(const unsigned short* xs, const int* ei32, Flags* fl) {
    if (threadIdx.x == 0 && blockIdx.x == 0) {
        int huge = 0;
        for (int i = 0; i < 1024; i += 2) {
            int e = (xs[i] >> 7) & 0xFF;
            if (e >= 0xC0) huge = 1;            // fp32 low-halves have random exponents
        }
        int odd_nonzero = 0;
        for (int i = 1; i < 512; i += 2)
            if (ei32[i] != 0) odd_nonzero = 1;  // int64 high words are all 0
        fl->f32 = huge;
        fl->i64 = !odd_nonzero;
    }
}

// ---- K1: degree sum + in-degree histogram + argmin(row==0) in one pass ----
__global__ void k_deg(const void* __restrict__ ei, const void* __restrict__ ew,
                      const Flags* __restrict__ fl,
                      float* __restrict__ deg, int* __restrict__ cnt, u64* __restrict__ minkey) {
    int e = blockIdx.x * blockDim.x + threadIdx.x;
    if (e >= NE) return;
    int f32 = fl->f32, i64 = fl->i64;
    int r = lde(ei, e, i64);
    int c = lde(ei, (size_t)NE + e, i64);
    float w = ldf(ew, e, f32);
    atomicAdd(&deg[c], w);
    atomicAdd(&cnt[c], 1);
    if (r == 0) {
        u64 key = ((u64)__float_as_uint(w) << 32) | (unsigned)e;  // w>=0: bits monotone
        atomicMin(minkey, key);
    }
}

// ---- K2: dinv for both layers ----
__global__ void k_dinv(const float* __restrict__ deg, const void* __restrict__ ei,
                       const void* __restrict__ ew, const Flags* __restrict__ fl,
                       const u64* __restrict__ minkey,
                       float* __restrict__ dinv1, float* __restrict__ dinv2) {
    int i = blockIdx.x * blockDim.x + threadIdx.x;
    if (i >= NN) return;
    int f32 = fl->f32, i64 = fl->i64;
    u64 k = *minkey;
    int eidx = (k == ~0ull) ? 0 : (int)(k & 0xffffffffu);  // argmin(all-inf)==0, like jnp
    int cmin = lde(ei, (size_t)NE + eidx, i64);
    float wmin = ldf(ew, eidx, f32);
    float d1 = deg[i] + 1.0f;                 // +1 for self loop
    float d2 = d1 - ((i == cmin) ? wmin : 0.0f);
    dinv1[i] = rsqrtf(d1);
    dinv2[i] = rsqrtf(d2);
}

// ---- K3: exclusive scan of cnt -> rowptr (single block, 1024 threads) ----
__global__ __launch_bounds__(1024) void k_scan(const int* __restrict__ cnt,
                                               int* __restrict__ rowptr) {
    __shared__ int part[1024];
    int t = threadIdx.x;
    const int CH = (NN + 1023) / 1024;  // 98
    int lo = t * CH, hi = lo + CH; if (hi > NN) hi = NN; if (lo > NN) lo = NN;
    int s = 0;
    for (int i = lo; i < hi; ++i) s += cnt[i];
    part[t] = s;
    // inclusive Hillis-Steele scan
    for (int off = 1; off < 1024; off <<= 1) {
        __syncthreads();
        int add = (t >= off) ? part[t - off] : 0;
        __syncthreads();
        part[t] += add;
    }
    __syncthreads();
    int run = part[t] - s;  // exclusive prefix of this chunk
    for (int i = lo; i < hi; ++i) { rowptr[i] = run; run += cnt[i]; }
    if (t == 1023) rowptr[NN] = part[1023];  // == NE
}

// ---- K4: placement — sort edges by destination (counting sort) ----
__global__ void k_place(const void* __restrict__ ei, const void* __restrict__ ew,
                        const Flags* __restrict__ fl, const u64* __restrict__ minkey,
                        const int* __restrict__ rowptr, int* __restrict__ cursor,
                        int* __restrict__ srcs, float* __restrict__ wsort,
                        int* __restrict__ delpos) {
    int e = blockIdx.x * blockDim.x + threadIdx.x;
    if (e >= NE) return;
    int f32 = fl->f32, i64 = fl->i64;
    int r = lde(ei, e, i64);
    int c = lde(ei, (size_t)NE + e, i64);
    float w = ldf(ew, e, f32);
    int pos = rowptr[c] + atomicAdd(&cursor[c], 1);
    srcs[pos] = r;
    wsort[pos] = w;
    u64 k = *minkey;
    int eidx = (k == ~0ull) ? 0 : (int)(k & 0xffffffffu);
    if (e == eidx) *delpos = pos;
}

// ---- K5: h1 = x @ W1 (bf16 out) ----
__global__ __launch_bounds__(256) void k_gemm1(const void* __restrict__ x,
                                               const void* __restrict__ W1,
                                               const Flags* __restrict__ fl,
                                               __hip_bfloat16* __restrict__ h1) {
    __shared__ float Ws[FIN * HID];  // 32 KB
    int t = threadIdx.x;
    int f32 = fl->f32;
    for (int i = t; i < FIN * HID; i += 256) Ws[i] = ldf(W1, i, f32);
    __syncthreads();
    int node = blockIdx.x * 16 + (t >> 4);  // 16 nodes/block, 16 threads/node
    if (node >= NN) return;
    int o4 = (t & 15) * 4;                  // 4 outputs/thread
    float a0 = 0.f, a1 = 0.f, a2 = 0.f, a3 = 0.f;
    if (f32) {
        const float* xr = (const float*)x + (size_t)node * FIN;
#pragma unroll 4
        for (int k = 0; k < FIN; ++k) {
            float xv = xr[k];
            const float* wr = &Ws[k * HID + o4];
            a0 += xv * wr[0]; a1 += xv * wr[1]; a2 += xv * wr[2]; a3 += xv * wr[3];
        }
    } else {
        const __hip_bfloat16* xr = (const __hip_bfloat16*)x + (size_t)node * FIN;
#pragma unroll 4
        for (int k = 0; k < FIN; ++k) {
            float xv = b2f(xr[k]);
            const float* wr = &Ws[k * HID + o4];
            a0 += xv * wr[0]; a1 += xv * wr[1]; a2 += xv * wr[2]; a3 += xv * wr[3];
        }
    }
    union { uint2 u; __hip_bfloat16 h[4]; } pk;
    pk.h[0] = __float2bfloat16(a0); pk.h[1] = __float2bfloat16(a1);
    pk.h[2] = __float2bfloat16(a2); pk.h[3] = __float2bfloat16(a3);
    *(uint2*)(h1 + (size_t)node * HID + o4) = pk.u;
}

// ---- K6: gather-aggregate layer 1 + fused epilogue (relu(agg + dinv^2 h + b)) ----
__global__ __launch_bounds__(256) void k_agg1(const int* __restrict__ rowptr,
                                              const int* __restrict__ srcs,
                                              const float* __restrict__ wsort,
                                              const float* __restrict__ dinv1,
                                              const __hip_bfloat16* __restrict__ h1,
                                              const void* __restrict__ b1,
                                              const Flags* __restrict__ fl,
                                              float* __restrict__ out1) {
    int t = threadIdx.x;
    int n = blockIdx.x * 16 + (t >> 4);  // 16 nodes/block, 16 threads/node
    if (n >= NN) return;
    int f = (t & 15) * 4;
    int f32 = fl->f32;
    float dn = dinv1[n];
    int p0 = rowptr[n], p1 = rowptr[n + 1];
    float a0 = 0.f, a1 = 0.f, a2 = 0.f, a3 = 0.f;
    for (int p = p0; p < p1; ++p) {
        int r = srcs[p];
        float cw = dinv1[r] * wsort[p];
        float x0, x1, x2, x3;
        ld4bf(h1 + (size_t)r * HID + f, x0, x1, x2, x3);
        a0 += cw * x0; a1 += cw * x1; a2 += cw * x2; a3 += cw * x3;
    }
    float x0, x1, x2, x3;
    ld4bf(h1 + (size_t)n * HID + f, x0, x1, x2, x3);
    float s = dn * dn;
    float4 o;
    o.x = fmaxf(dn * a0 + s * x0 + ldf(b1, f + 0, f32), 0.f);
    o.y = fmaxf(dn * a1 + s * x1 + ldf(b1, f + 1, f32), 0.f);
    o.z = fmaxf(dn * a2 + s * x2 + ldf(b1, f + 2, f32), 0.f);
    o.w = fmaxf(dn * a3 + s * x3 + ldf(b1, f + 3, f32), 0.f);
    *(float4*)(out1 + (size_t)n * HID + f) = o;
}

// ---- K7: h2 = out1 @ W2 ----
__global__ __launch_bounds__(256) void k_gemm2(const float* __restrict__ out1,
                                               const void* __restrict__ W2,
                                               const Flags* __restrict__ fl,
                                               float* __restrict__ h2) {
    __shared__ float Ws[HID * COUT];  // 4 KB
    int t = threadIdx.x;
    int f32 = fl->f32;
    for (int i = t; i < HID * COUT; i += 256) Ws[i] = ldf(W2, i, f32);
    __syncthreads();
    int node = blockIdx.x * 64 + (t >> 2);  // 64 nodes/block, 4 threads/node
    if (node >= NN) return;
    int o4 = (t & 3) * 4;
    const float* xr = out1 + (size_t)node * HID;
    float a0 = 0.f, a1 = 0.f, a2 = 0.f, a3 = 0.f;
#pragma unroll 4
    for (int k = 0; k < HID; ++k) {
        float xv = xr[k];
        const float* wr = &Ws[k * COUT + o4];
        a0 += xv * wr[0]; a1 += xv * wr[1]; a2 += xv * wr[2]; a3 += xv * wr[3];
    }
    float* ho = h2 + (size_t)node * COUT + o4;
    ho[0] = a0; ho[1] = a1; ho[2] = a2; ho[3] = a3;
}

// ---- K8: gather-aggregate layer 2 + fused epilogue -> out (fp32 or bf16) ----
__global__ __launch_bounds__(256) void k_agg2(const int* __restrict__ rowptr,
                                              const int* __restrict__ srcs,
                                              const float* __restrict__ wsort,
                                              const float* __restrict__ dinv2,
                                              const float* __restrict__ h2,
                                              const void* __restrict__ bias2,
                                              const Flags* __restrict__ fl,
                                              const int* __restrict__ delpos,
                                              void* __restrict__ out) {
    int t = threadIdx.x;
    int n = blockIdx.x * 64 + (t >> 2);  // 64 nodes/block, 4 threads/node
    if (n >= NN) return;
    int f = (t & 3) * 4;
    int f32 = fl->f32;
    int dp = *delpos;
    float dn = dinv2[n];
    int p0 = rowptr[n], p1 = rowptr[n + 1];
    float a0 = 0.f, a1 = 0.f, a2 = 0.f, a3 = 0.f;
    for (int p = p0; p < p1; ++p) {
        int r = srcs[p];
        float w = (p == dp) ? 0.f : wsort[p];
        float cw = dinv2[r] * w;
        const float4 hv = *(const float4*)(h2 + (size_t)r * COUT + f);
        a0 += cw * hv.x; a1 += cw * hv.y; a2 += cw * hv.z; a3 += cw * hv.w;
    }
    float s = dn * dn;
    const float4 hn = *(const float4*)(h2 + (size_t)n * COUT + f);
    float o0 = dn * a0 + s * hn.x + ldf(bias2, f + 0, f32);
    float o1 = dn * a1 + s * hn.y + ldf(bias2, f + 1, f32);
    float o2 = dn * a2 + s * hn.z + ldf(bias2, f + 2, f32);
    float o3 = dn * a3 + s * hn.w + ldf(bias2, f + 3, f32);
    size_t idx = (size_t)n * COUT + f;
    if (f32) {
        float* op = (float*)out + idx;
        op[0] = o0; op[1] = o1; op[2] = o2; op[3] = o3;
    } else {
        union { uint2 u; __hip_bfloat16 h[4]; } pk;
        pk.h[0] = __float2bfloat16(o0); pk.h[1] = __float2bfloat16(o1);
        pk.h[2] = __float2bfloat16(o2); pk.h[3] = __float2bfloat16(o3);
        *(uint2*)((__hip_bfloat16*)out + idx) = pk.u;
    }
}

extern "C" void kernel_launch(void* const* d_in, const int* in_sizes, int n_in,
                              void* d_out, int out_size, void* d_ws, size_t ws_size,
                              hipStream_t stream) {
    const void* x  = d_in[0];
    const void* ei = d_in[1];
    const void* ew = d_in[2];
    const void* W1 = d_in[3];
    const void* b1 = d_in[4];
    const void* W2 = d_in[5];
    const void* b2 = d_in[6];

    // workspace layout: ~60 MB total (fits the proven <=65 MB envelope)
    char* wsb = (char*)d_ws;
    float* deg    = (float*)wsb;                       wsb += (size_t)NN * 4;
    float* dinv1  = (float*)wsb;                       wsb += (size_t)NN * 4;
    float* dinv2  = (float*)wsb;                       wsb += (size_t)NN * 4;
    int*   cnt    = (int*)wsb;                         wsb += (size_t)NN * 4;
    int*   cursor = (int*)wsb;                         wsb += (size_t)NN * 4;
    int*   rowptr = (int*)wsb;                         wsb += (size_t)(NN + 1) * 4;
    // align to 16
    wsb = (char*)(((uintptr_t)wsb + 15) & ~(uintptr_t)15);
    int*   srcs   = (int*)wsb;                         wsb += (size_t)NE * 4;
    float* wsort  = (float*)wsb;                       wsb += (size_t)NE * 4;
    __hip_bfloat16* h1 = (__hip_bfloat16*)wsb;         wsb += (size_t)NN * HID * 2;
    float* out1   = (float*)wsb;                       wsb += (size_t)NN * HID * 4;
    float* h2     = (float*)wsb;                       wsb += (size_t)NN * COUT * 4;
    u64*   minkey = (u64*)wsb;                         wsb += 8;
    Flags* fl     = (Flags*)wsb;                       wsb += 8;
    int*   delpos = (int*)wsb;                         wsb += 8;

    hipMemsetAsync(deg,    0, (size_t)NN * 4, stream);
    hipMemsetAsync(cnt,    0, (size_t)NN * 4, stream);
    hipMemsetAsync(cursor, 0, (size_t)NN * 4, stream);
    hipMemsetAsync(minkey, 0xFF, 8, stream);
    hipMemsetAsync(delpos, 0xFF, 4, stream);

    k_detect<<<1, 64, 0, stream>>>((const unsigned short*)x, (const int*)ei, fl);
    k_deg<<<(NE + 255) / 256, 256, 0, stream>>>(ei, ew, fl, deg, cnt, minkey);
    k_dinv<<<(NN + 255) / 256, 256, 0, stream>>>(deg, ei, ew, fl, minkey, dinv1, dinv2);
    k_scan<<<1, 1024, 0, stream>>>(cnt, rowptr);
    k_place<<<(NE + 255) / 256, 256, 0, stream>>>(ei, ew, fl, minkey, rowptr, cursor,
                                                  srcs, wsort, delpos);
    k_gemm1<<<(NN + 15) / 16, 256, 0, stream>>>(x, W1, fl, h1);
    k_agg1<<<(NN + 15) / 16, 256, 0, stream>>>(rowptr, srcs, wsort, dinv1, h1, b1, fl, out1);
    k_gemm2<<<(NN + 63) / 64, 256, 0, stream>>>(out1, W2, fl, h2);
    k_agg2<<<(NN + 63) / 64, 256, 0, stream>>>(rowptr, srcs, wsort, dinv2, h2, b2, fl,
                                               delpos, d_out);
}

// Round 4
// 625.471 us; speedup vs baseline: 3.1320x; 1.2787x over previous
//
#include <hip/hip_runtime.h>
#include <hip/hip_bf16.h>
#include <stdint.h>

#define NN 100000
#define NE 1600000
#define FIN 128
#define HID 64
#define COUT 16

#define SCAN_CH 250   // nodes per scan block
#define SCAN_NB 400   // scan blocks (400*250 = 100000)

typedef unsigned long long u64;

struct Flags { int f32; int i64; };

__device__ __forceinline__ float b2f(__hip_bfloat16 v) { return __bfloat162float(v); }

// adaptive float load: fp32 buffer or bf16 buffer
__device__ __forceinline__ float ldf(const void* p, size_t i, int f32) {
    return f32 ? ((const float*)p)[i]
               : __bfloat162float(((const __hip_bfloat16*)p)[i]);
}
// adaptive edge-index load: int32 or int64 buffer, logical index i in [0, 2*NE)
__device__ __forceinline__ int lde(const void* p, size_t i, int i64) {
    return i64 ? (int)((const long long*)p)[i] : ((const int*)p)[i];
}
// load 4 consecutive bf16 (8B-aligned) -> 4 floats
__device__ __forceinline__ void ld4bf(const __hip_bfloat16* p, float& x0, float& x1,
                                      float& x2, float& x3) {
    union { uint2 u; __hip_bfloat16 h[4]; } v;
    v.u = *(const uint2*)p;
    x0 = b2f(v.h[0]); x1 = b2f(v.h[1]); x2 = b2f(v.h[2]); x3 = b2f(v.h[3]);
}

// ---- K0: detect input dtypes on-device (same work every call; deterministic) ----
__global__ void k_detect(const unsigned short* xs, const int* ei32, Flags* fl) {
    if (threadIdx.x == 0 && blockIdx.x == 0) {
        int huge = 0;
        for (int i = 0; i < 1024; i += 2) {
            int e = (xs[i] >> 7) & 0xFF;
            if (e >= 0xC0) huge = 1;            // fp32 low-halves have random exponents
        }
        int odd_nonzero = 0;
        for (int i = 1; i < 512; i += 2)
            if (ei32[i] != 0) odd_nonzero = 1;  // int64 high words are all 0
        fl->f32 = huge;
        fl->i64 = !odd_nonzero;
    }
}

// ---- K1: degree sum + in-degree histogram + argmin(row==0) in one pass ----
__global__ void k_deg(const void* __restrict__ ei, const void* __restrict__ ew,
                      const Flags* __restrict__ fl,
                      float* __restrict__ deg, int* __restrict__ cnt, u64* __restrict__ minkey) {
    int e = blockIdx.x * blockDim.x + threadIdx.x;
    if (e >= NE) return;
    int f32 = fl->f32, i64 = fl->i64;
    int r = lde(ei, e, i64);
    int c = lde(ei, (size_t)NE + e, i64);
    float w = ldf(ew, e, f32);
    atomicAdd(&deg[c], w);
    atomicAdd(&cnt[c], 1);
    if (r == 0) {
        u64 key = ((u64)__float_as_uint(w) << 32) | (unsigned)e;  // w>=0: bits monotone
        atomicMin(minkey, key);
    }
}

// ---- K2: dinv for both layers ----
__global__ void k_dinv(const float* __restrict__ deg, const void* __restrict__ ei,
                       const void* __restrict__ ew, const Flags* __restrict__ fl,
                       const u64* __restrict__ minkey,
                       float* __restrict__ dinv1, float* __restrict__ dinv2) {
    int i = blockIdx.x * blockDim.x + threadIdx.x;
    if (i >= NN) return;
    int f32 = fl->f32, i64 = fl->i64;
    u64 k = *minkey;
    int eidx = (k == ~0ull) ? 0 : (int)(k & 0xffffffffu);  // argmin(all-inf)==0, like jnp
    int cmin = lde(ei, (size_t)NE + eidx, i64);
    float wmin = ldf(ew, eidx, f32);
    float d1 = deg[i] + 1.0f;                 // +1 for self loop
    float d2 = d1 - ((i == cmin) ? wmin : 0.0f);
    dinv1[i] = rsqrtf(d1);
    dinv2[i] = rsqrtf(d2);
}

// ---- K3a: per-block local exclusive scan of cnt (400 blocks x 250 nodes) ----
__global__ __launch_bounds__(256) void k_scanA(const int* __restrict__ cnt,
                                               int* __restrict__ rowptr,
                                               int* __restrict__ blocksum) {
    __shared__ int sm[256];
    int b = blockIdx.x, t = threadIdx.x;
    int i = b * SCAN_CH + t;
    int v = (t < SCAN_CH) ? cnt[i] : 0;
    sm[t] = v;
    for (int off = 1; off < 256; off <<= 1) {
        __syncthreads();
        int add = (t >= off) ? sm[t - off] : 0;
        __syncthreads();
        sm[t] += add;
    }
    __syncthreads();
    if (t < SCAN_CH) rowptr[i] = sm[t] - v;       // block-local exclusive prefix
    if (t == 255) blocksum[b] = sm[255];
}

// ---- K3b: scan the 400 block sums (1 block) ----
__global__ __launch_bounds__(512) void k_scanB(const int* __restrict__ blocksum,
                                               int* __restrict__ blockoff,
                                               int* __restrict__ rowptr) {
    __shared__ int sm[512];
    int t = threadIdx.x;
    int v = (t < SCAN_NB) ? blocksum[t] : 0;
    sm[t] = v;
    for (int off = 1; off < 512; off <<= 1) {
        __syncthreads();
        int add = (t >= off) ? sm[t - off] : 0;
        __syncthreads();
        sm[t] += add;
    }
    __syncthreads();
    if (t < SCAN_NB) blockoff[t] = sm[t] - v;     // exclusive block offset
    if (t == 511) rowptr[NN] = sm[511];           // == NE
}

// ---- K3c: add block offsets ----
__global__ __launch_bounds__(256) void k_scanC(const int* __restrict__ blockoff,
                                               int* __restrict__ rowptr) {
    int b = blockIdx.x, t = threadIdx.x;
    if (t < SCAN_CH) rowptr[b * SCAN_CH + t] += blockoff[b];
}

// ---- K4: placement — sort edges by destination (counting sort), packed (src,w) ----
__global__ void k_place(const void* __restrict__ ei, const void* __restrict__ ew,
                        const Flags* __restrict__ fl, const u64* __restrict__ minkey,
                        const int* __restrict__ rowptr, int* __restrict__ cursor,
                        int2* __restrict__ epack, int* __restrict__ delpos) {
    int e = blockIdx.x * blockDim.x + threadIdx.x;
    if (e >= NE) return;
    int f32 = fl->f32, i64 = fl->i64;
    int r = lde(ei, e, i64);
    int c = lde(ei, (size_t)NE + e, i64);
    float w = ldf(ew, e, f32);
    int pos = rowptr[c] + atomicAdd(&cursor[c], 1);
    epack[pos] = make_int2(r, __float_as_int(w));
    u64 k = *minkey;
    int eidx = (k == ~0ull) ? 0 : (int)(k & 0xffffffffu);
    if (e == eidx) *delpos = pos;
}

// ---- K5: h1 = x @ W1 (bf16 out) ----
__global__ __launch_bounds__(256) void k_gemm1(const void* __restrict__ x,
                                               const void* __restrict__ W1,
                                               const Flags* __restrict__ fl,
                                               __hip_bfloat16* __restrict__ h1) {
    __shared__ float Ws[FIN * HID];  // 32 KB
    int t = threadIdx.x;
    int f32 = fl->f32;
    for (int i = t; i < FIN * HID; i += 256) Ws[i] = ldf(W1, i, f32);
    __syncthreads();
    int node = blockIdx.x * 16 + (t >> 4);  // 16 nodes/block, 16 threads/node
    if (node >= NN) return;
    int o4 = (t & 15) * 4;                  // 4 outputs/thread
    float a0 = 0.f, a1 = 0.f, a2 = 0.f, a3 = 0.f;
    if (f32) {
        const float* xr = (const float*)x + (size_t)node * FIN;
#pragma unroll 4
        for (int k = 0; k < FIN; ++k) {
            float xv = xr[k];
            const float* wr = &Ws[k * HID + o4];
            a0 += xv * wr[0]; a1 += xv * wr[1]; a2 += xv * wr[2]; a3 += xv * wr[3];
        }
    } else {
        const __hip_bfloat16* xr = (const __hip_bfloat16*)x + (size_t)node * FIN;
#pragma unroll 4
        for (int k = 0; k < FIN; ++k) {
            float xv = b2f(xr[k]);
            const float* wr = &Ws[k * HID + o4];
            a0 += xv * wr[0]; a1 += xv * wr[1]; a2 += xv * wr[2]; a3 += xv * wr[3];
        }
    }
    union { uint2 u; __hip_bfloat16 h[4]; } pk;
    pk.h[0] = __float2bfloat16(a0); pk.h[1] = __float2bfloat16(a1);
    pk.h[2] = __float2bfloat16(a2); pk.h[3] = __float2bfloat16(a3);
    *(uint2*)(h1 + (size_t)node * HID + o4) = pk.u;
}

// ---- K6: gather-aggregate layer 1 + fused epilogue (relu(agg + dinv^2 h + b)) ----
__global__ __launch_bounds__(256) void k_agg1(const int* __restrict__ rowptr,
                                              const int2* __restrict__ epack,
                                              const float* __restrict__ dinv1,
                                              const __hip_bfloat16* __restrict__ h1,
                                              const void* __restrict__ b1,
                                              const Flags* __restrict__ fl,
                                              float* __restrict__ out1) {
    int t = threadIdx.x;
    int n = blockIdx.x * 16 + (t >> 4);  // 16 nodes/block, 16 threads/node
    if (n >= NN) return;
    int f = (t & 15) * 4;
    int f32 = fl->f32;
    float dn = dinv1[n];
    int p0 = rowptr[n], p1 = rowptr[n + 1];
    float a0 = 0.f, a1 = 0.f, a2 = 0.f, a3 = 0.f;
    for (int p = p0; p < p1; ++p) {
        int2 ev = epack[p];
        int r = ev.x;
        float cw = dinv1[r] * __int_as_float(ev.y);
        float x0, x1, x2, x3;
        ld4bf(h1 + (size_t)r * HID + f, x0, x1, x2, x3);
        a0 += cw * x0; a1 += cw * x1; a2 += cw * x2; a3 += cw * x3;
    }
    float x0, x1, x2, x3;
    ld4bf(h1 + (size_t)n * HID + f, x0, x1, x2, x3);
    float s = dn * dn;
    float4 o;
    o.x = fmaxf(dn * a0 + s * x0 + ldf(b1, f + 0, f32), 0.f);
    o.y = fmaxf(dn * a1 + s * x1 + ldf(b1, f + 1, f32), 0.f);
    o.z = fmaxf(dn * a2 + s * x2 + ldf(b1, f + 2, f32), 0.f);
    o.w = fmaxf(dn * a3 + s * x3 + ldf(b1, f + 3, f32), 0.f);
    *(float4*)(out1 + (size_t)n * HID + f) = o;
}

// ---- K7: h2 = out1 @ W2 ----
__global__ __launch_bounds__(256) void k_gemm2(const float* __restrict__ out1,
                                               const void* __restrict__ W2,
                                               const Flags* __restrict__ fl,
                                               float* __restrict__ h2) {
    __shared__ float Ws[HID * COUT];  // 4 KB
    int t = threadIdx.x;
    int f32 = fl->f32;
    for (int i = t; i < HID * COUT; i += 256) Ws[i] = ldf(W2, i, f32);
    __syncthreads();
    int node = blockIdx.x * 64 + (t >> 2);  // 64 nodes/block, 4 threads/node
    if (node >= NN) return;
    int o4 = (t & 3) * 4;
    const float* xr = out1 + (size_t)node * HID;
    float a0 = 0.f, a1 = 0.f, a2 = 0.f, a3 = 0.f;
#pragma unroll 4
    for (int k = 0; k < HID; ++k) {
        float xv = xr[k];
        const float* wr = &Ws[k * COUT + o4];
        a0 += xv * wr[0]; a1 += xv * wr[1]; a2 += xv * wr[2]; a3 += xv * wr[3];
    }
    float* ho = h2 + (size_t)node * COUT + o4;
    ho[0] = a0; ho[1] = a1; ho[2] = a2; ho[3] = a3;
}

// ---- K8: gather-aggregate layer 2 + fused epilogue -> out (fp32 or bf16) ----
__global__ __launch_bounds__(256) void k_agg2(const int* __restrict__ rowptr,
                                              const int2* __restrict__ epack,
                                              const float* __restrict__ dinv2,
                                              const float* __restrict__ h2,
                                              const void* __restrict__ bias2,
                                              const Flags* __restrict__ fl,
                                              const int* __restrict__ delpos,
                                              void* __restrict__ out) {
    int t = threadIdx.x;
    int n = blockIdx.x * 64 + (t >> 2);  // 64 nodes/block, 4 threads/node
    if (n >= NN) return;
    int f = (t & 3) * 4;
    int f32 = fl->f32;
    int dp = *delpos;
    float dn = dinv2[n];
    int p0 = rowptr[n], p1 = rowptr[n + 1];
    float a0 = 0.f, a1 = 0.f, a2 = 0.f, a3 = 0.f;
    for (int p = p0; p < p1; ++p) {
        int2 ev = epack[p];
        int r = ev.x;
        float w = (p == dp) ? 0.f : __int_as_float(ev.y);
        float cw = dinv2[r] * w;
        const float4 hv = *(const float4*)(h2 + (size_t)r * COUT + f);
        a0 += cw * hv.x; a1 += cw * hv.y; a2 += cw * hv.z; a3 += cw * hv.w;
    }
    float s = dn * dn;
    const float4 hn = *(const float4*)(h2 + (size_t)n * COUT + f);
    float o0 = dn * a0 + s * hn.x + ldf(bias2, f + 0, f32);
    float o1 = dn * a1 + s * hn.y + ldf(bias2, f + 1, f32);
    float o2 = dn * a2 + s * hn.z + ldf(bias2, f + 2, f32);
    float o3 = dn * a3 + s * hn.w + ldf(bias2, f + 3, f32);
    size_t idx = (size_t)n * COUT + f;
    if (f32) {
        float* op = (float*)out + idx;
        op[0] = o0; op[1] = o1; op[2] = o2; op[3] = o3;
    } else {
        union { uint2 u; __hip_bfloat16 h[4]; } pk;
        pk.h[0] = __float2bfloat16(o0); pk.h[1] = __float2bfloat16(o1);
        pk.h[2] = __float2bfloat16(o2); pk.h[3] = __float2bfloat16(o3);
        *(uint2*)((__hip_bfloat16*)out + idx) = pk.u;
    }
}

extern "C" void kernel_launch(void* const* d_in, const int* in_sizes, int n_in,
                              void* d_out, int out_size, void* d_ws, size_t ws_size,
                              hipStream_t stream) {
    const void* x  = d_in[0];
    const void* ei = d_in[1];
    const void* ew = d_in[2];
    const void* W1 = d_in[3];
    const void* b1 = d_in[4];
    const void* W2 = d_in[5];
    const void* b2 = d_in[6];

    // workspace layout: ~60 MB total (fits the proven <=65 MB envelope)
    char* wsb = (char*)d_ws;
    float* deg     = (float*)wsb;                      wsb += (size_t)NN * 4;
    float* dinv1   = (float*)wsb;                      wsb += (size_t)NN * 4;
    float* dinv2   = (float*)wsb;                      wsb += (size_t)NN * 4;
    int*   cnt     = (int*)wsb;                        wsb += (size_t)NN * 4;
    int*   cursor  = (int*)wsb;                        wsb += (size_t)NN * 4;
    int*   rowptr  = (int*)wsb;                        wsb += (size_t)(NN + 1) * 4;
    int*   blocksum= (int*)wsb;                        wsb += (size_t)SCAN_NB * 4;
    int*   blockoff= (int*)wsb;                        wsb += (size_t)SCAN_NB * 4;
    // align to 16
    wsb = (char*)(((uintptr_t)wsb + 15) & ~(uintptr_t)15);
    int2*  epack   = (int2*)wsb;                       wsb += (size_t)NE * 8;
    __hip_bfloat16* h1 = (__hip_bfloat16*)wsb;         wsb += (size_t)NN * HID * 2;
    float* out1    = (float*)wsb;                      wsb += (size_t)NN * HID * 4;
    float* h2      = (float*)wsb;                      wsb += (size_t)NN * COUT * 4;
    u64*   minkey  = (u64*)wsb;                        wsb += 8;
    Flags* fl      = (Flags*)wsb;                      wsb += 8;
    int*   delpos  = (int*)wsb;                        wsb += 8;

    hipMemsetAsync(deg,    0, (size_t)NN * 4, stream);
    hipMemsetAsync(cnt,    0, (size_t)NN * 4, stream);
    hipMemsetAsync(cursor, 0, (size_t)NN * 4, stream);
    hipMemsetAsync(minkey, 0xFF, 8, stream);
    hipMemsetAsync(delpos, 0xFF, 4, stream);

    k_detect<<<1, 64, 0, stream>>>((const unsigned short*)x, (const int*)ei, fl);
    k_deg<<<(NE + 255) / 256, 256, 0, stream>>>(ei, ew, fl, deg, cnt, minkey);
    k_dinv<<<(NN + 255) / 256, 256, 0, stream>>>(deg, ei, ew, fl, minkey, dinv1, dinv2);
    k_scanA<<<SCAN_NB, 256, 0, stream>>>(cnt, rowptr, blocksum);
    k_scanB<<<1, 512, 0, stream>>>(blocksum, blockoff, rowptr);
    k_scanC<<<SCAN_NB, 256, 0, stream>>>(blockoff, rowptr);
    k_place<<<(NE + 255) / 256, 256, 0, stream>>>(ei, ew, fl, minkey, rowptr, cursor,
                                                  epack, delpos);
    k_gemm1<<<(NN + 15) / 16, 256, 0, stream>>>(x, W1, fl, h1);
    k_agg1<<<(NN + 15) / 16, 256, 0, stream>>>(rowptr, epack, dinv1, h1, b1, fl, out1);
    k_gemm2<<<(NN + 63) / 64, 256, 0, stream>>>(out1, W2, fl, h2);
    k_agg2<<<(NN + 63) / 64, 256, 0, stream>>>(rowptr, epack, dinv2, h2, b2, fl,
                                               delpos, d_out);
}

// Round 5
// 538.073 us; speedup vs baseline: 3.6407x; 1.1624x over previous
//
#include <hip/hip_runtime.h>
#include <hip/hip_bf16.h>
#include <stdint.h>

#define NN 100000
#define NE 1600000
#define FIN 128
#define HID 64
#define COUT 16

#define NC 8                    // colors (sub-bins per node)
#define NBINS (NN * NC)         // 800000
#define SC 4                    // bins per thread in scan
#define SCAN_T 256
#define SCAN_SPAN (SCAN_T * SC) // 1024 bins per scan block
#define SCAN_NB ((NBINS + SCAN_SPAN - 1) / SCAN_SPAN)  // 782

#define MASK44 ((1ull << 44) - 1)

typedef unsigned long long u64;

struct Flags { int f32; int i64; };

__device__ __forceinline__ float b2f(__hip_bfloat16 v) { return __bfloat162float(v); }

// adaptive float load: fp32 buffer or bf16 buffer
__device__ __forceinline__ float ldf(const void* p, size_t i, int f32) {
    return f32 ? ((const float*)p)[i]
               : __bfloat162float(((const __hip_bfloat16*)p)[i]);
}
// adaptive edge-index load: int32 or int64 buffer, logical index i in [0, 2*NE)
__device__ __forceinline__ int lde(const void* p, size_t i, int i64) {
    return i64 ? (int)((const long long*)p)[i] : ((const int*)p)[i];
}
// load 4 consecutive bf16 (8B-aligned) -> 4 floats
__device__ __forceinline__ void ld4bf(const __hip_bfloat16* p, float& x0, float& x1,
                                      float& x2, float& x3) {
    union { uint2 u; __hip_bfloat16 h[4]; } v;
    v.u = *(const uint2*)p;
    x0 = b2f(v.h[0]); x1 = b2f(v.h[1]); x2 = b2f(v.h[2]); x3 = b2f(v.h[3]);
}

// ---- K0: detect input dtypes on-device (same work every call; deterministic) ----
__global__ void k_detect(const unsigned short* xs, const int* ei32, Flags* fl) {
    if (threadIdx.x == 0 && blockIdx.x == 0) {
        int huge = 0;
        for (int i = 0; i < 1024; i += 2) {
            int e = (xs[i] >> 7) & 0xFF;
            if (e >= 0xC0) huge = 1;            // fp32 low-halves have random exponents
        }
        int odd_nonzero = 0;
        for (int i = 1; i < 512; i += 2)
            if (ei32[i] != 0) odd_nonzero = 1;  // int64 high words are all 0
        fl->f32 = huge;
        fl->i64 = !odd_nonzero;
    }
}

// ---- K1: packed per-(node,color) histogram: count<<44 | fixed-point weight sum ----
// one u64 atomic per edge, spread over 6.4 MB (16 atomics/line avg vs 256 before)
__global__ void k_hist(const void* __restrict__ ei, const void* __restrict__ ew,
                       const Flags* __restrict__ fl,
                       u64* __restrict__ hist8, u64* __restrict__ minkey) {
    int e = blockIdx.x * blockDim.x + threadIdx.x;
    if (e >= NE) return;
    int color = blockIdx.x & (NC - 1);
    int f32 = fl->f32, i64 = fl->i64;
    int r = lde(ei, e, i64);
    int c = lde(ei, (size_t)NE + e, i64);
    float w = ldf(ew, e, f32);
    // w in [0,1]: w*2^32 exact in double (24-bit mantissa), < 2^33 << 2^44
    u64 add = (1ull << 44) | (u64)((double)w * 4294967296.0);
    atomicAdd(&hist8[(size_t)c * NC + color], add);
    if (r == 0) {
        u64 key = ((u64)__float_as_uint(w) << 32) | (unsigned)e;  // w>=0: bits monotone
        atomicMin(minkey, key);
    }
}

// ---- K2: dinv for both layers (deg recovered from fixed-point bins; exact) ----
__global__ void k_dinv(const u64* __restrict__ hist8, const void* __restrict__ ei,
                       const void* __restrict__ ew, const Flags* __restrict__ fl,
                       const u64* __restrict__ minkey,
                       float* __restrict__ dinv1, float* __restrict__ dinv2) {
    int i = blockIdx.x * blockDim.x + threadIdx.x;
    if (i >= NN) return;
    int f32 = fl->f32, i64 = fl->i64;
    u64 wsum = 0;
#pragma unroll
    for (int c = 0; c < NC; ++c) wsum += hist8[(size_t)i * NC + c] & MASK44;
    float deg = (float)((double)wsum * (1.0 / 4294967296.0));
    u64 k = *minkey;
    int eidx = (k == ~0ull) ? 0 : (int)(k & 0xffffffffu);  // argmin(all-inf)==0, like jnp
    int cmin = lde(ei, (size_t)NE + eidx, i64);
    float wmin = ldf(ew, eidx, f32);
    float d1 = deg + 1.0f;                    // +1 for self loop
    float d2 = d1 - ((i == cmin) ? wmin : 0.0f);
    dinv1[i] = rsqrtf(d1);
    dinv2[i] = rsqrtf(d2);
}

// ---- K3a: per-block local exclusive scan of bin counts (782 blocks x 1024 bins) ----
__global__ __launch_bounds__(SCAN_T) void k_scanA(const u64* __restrict__ hist8,
                                                  int* __restrict__ rowptrB,
                                                  int* __restrict__ blocksum) {
    __shared__ int sm[SCAN_T];
    int b = blockIdx.x, t = threadIdx.x;
    int base = b * SCAN_SPAN + t * SC;
    int v[SC];
    int s = 0;
#pragma unroll
    for (int j = 0; j < SC; ++j) {
        int idx = base + j;
        v[j] = (idx < NBINS) ? (int)(hist8[idx] >> 44) : 0;
        s += v[j];
    }
    sm[t] = s;
    for (int off = 1; off < SCAN_T; off <<= 1) {
        __syncthreads();
        int add = (t >= off) ? sm[t - off] : 0;
        __syncthreads();
        sm[t] += add;
    }
    __syncthreads();
    int run = sm[t] - s;  // exclusive prefix within block
#pragma unroll
    for (int j = 0; j < SC; ++j) {
        int idx = base + j;
        if (idx < NBINS) rowptrB[idx] = run;
        run += v[j];
    }
    if (t == SCAN_T - 1) blocksum[b] = sm[SCAN_T - 1];
}

// ---- K3b: scan the 782 block sums (1 block, 1024 threads) ----
__global__ __launch_bounds__(1024) void k_scanB(const int* __restrict__ blocksum,
                                                int* __restrict__ blockoff,
                                                int* __restrict__ rowptrB) {
    __shared__ int sm[1024];
    int t = threadIdx.x;
    int v = (t < SCAN_NB) ? blocksum[t] : 0;
    sm[t] = v;
    for (int off = 1; off < 1024; off <<= 1) {
        __syncthreads();
        int add = (t >= off) ? sm[t - off] : 0;
        __syncthreads();
        sm[t] += add;
    }
    __syncthreads();
    if (t < SCAN_NB) blockoff[t] = sm[t] - v;     // exclusive block offset
    if (t == 1023) rowptrB[NBINS] = sm[1023];     // == NE
}

// ---- K3c: add block offsets ----
__global__ __launch_bounds__(SCAN_T) void k_scanC(const int* __restrict__ blockoff,
                                                  int* __restrict__ rowptrB) {
    int b = blockIdx.x, t = threadIdx.x;
    int base = b * SCAN_SPAN + t * SC;
    int off = blockoff[b];
#pragma unroll
    for (int j = 0; j < SC; ++j) {
        int idx = base + j;
        if (idx < NBINS) rowptrB[idx] += off;
    }
}

// ---- K4: placement — counting sort by (dest,color) bin, packed (src,w) ----
__global__ void k_place(const void* __restrict__ ei, const void* __restrict__ ew,
                        const Flags* __restrict__ fl, const u64* __restrict__ minkey,
                        const int* __restrict__ rowptrB, int* __restrict__ cursorB,
                        int2* __restrict__ epack, int* __restrict__ delpos) {
    int e = blockIdx.x * blockDim.x + threadIdx.x;
    if (e >= NE) return;
    int color = blockIdx.x & (NC - 1);   // MUST match k_hist's color formula
    int f32 = fl->f32, i64 = fl->i64;
    int r = lde(ei, e, i64);
    int c = lde(ei, (size_t)NE + e, i64);
    float w = ldf(ew, e, f32);
    int bin = c * NC + color;
    int pos = rowptrB[bin] + atomicAdd(&cursorB[bin], 1);
    epack[pos] = make_int2(r, __float_as_int(w));
    u64 k = *minkey;
    int eidx = (k == ~0ull) ? 0 : (int)(k & 0xffffffffu);
    if (e == eidx) *delpos = pos;
}

// ---- K5: h1 = x @ W1 (bf16 out) ----
__global__ __launch_bounds__(256) void k_gemm1(const void* __restrict__ x,
                                               const void* __restrict__ W1,
                                               const Flags* __restrict__ fl,
                                               __hip_bfloat16* __restrict__ h1) {
    __shared__ float Ws[FIN * HID];  // 32 KB
    int t = threadIdx.x;
    int f32 = fl->f32;
    for (int i = t; i < FIN * HID; i += 256) Ws[i] = ldf(W1, i, f32);
    __syncthreads();
    int node = blockIdx.x * 16 + (t >> 4);  // 16 nodes/block, 16 threads/node
    if (node >= NN) return;
    int o4 = (t & 15) * 4;                  // 4 outputs/thread
    float a0 = 0.f, a1 = 0.f, a2 = 0.f, a3 = 0.f;
    if (f32) {
        const float* xr = (const float*)x + (size_t)node * FIN;
#pragma unroll 4
        for (int k = 0; k < FIN; ++k) {
            float xv = xr[k];
            const float* wr = &Ws[k * HID + o4];
            a0 += xv * wr[0]; a1 += xv * wr[1]; a2 += xv * wr[2]; a3 += xv * wr[3];
        }
    } else {
        const __hip_bfloat16* xr = (const __hip_bfloat16*)x + (size_t)node * FIN;
#pragma unroll 4
        for (int k = 0; k < FIN; ++k) {
            float xv = b2f(xr[k]);
            const float* wr = &Ws[k * HID + o4];
            a0 += xv * wr[0]; a1 += xv * wr[1]; a2 += xv * wr[2]; a3 += xv * wr[3];
        }
    }
    union { uint2 u; __hip_bfloat16 h[4]; } pk;
    pk.h[0] = __float2bfloat16(a0); pk.h[1] = __float2bfloat16(a1);
    pk.h[2] = __float2bfloat16(a2); pk.h[3] = __float2bfloat16(a3);
    *(uint2*)(h1 + (size_t)node * HID + o4) = pk.u;
}

// ---- K6: gather-aggregate layer 1 + fused epilogue (relu(agg + dinv^2 h + b)) ----
__global__ __launch_bounds__(256) void k_agg1(const int* __restrict__ rowptrB,
                                              const int2* __restrict__ epack,
                                              const float* __restrict__ dinv1,
                                              const __hip_bfloat16* __restrict__ h1,
                                              const void* __restrict__ b1,
                                              const Flags* __restrict__ fl,
                                              float* __restrict__ out1) {
    int t = threadIdx.x;
    int n = blockIdx.x * 16 + (t >> 4);  // 16 nodes/block, 16 threads/node
    if (n >= NN) return;
    int f = (t & 15) * 4;
    int f32 = fl->f32;
    float dn = dinv1[n];
    int p0 = rowptrB[(size_t)n * NC], p1 = rowptrB[(size_t)(n + 1) * NC];
    float a0 = 0.f, a1 = 0.f, a2 = 0.f, a3 = 0.f;
    for (int p = p0; p < p1; ++p) {
        int2 ev = epack[p];
        int r = ev.x;
        float cw = dinv1[r] * __int_as_float(ev.y);
        float x0, x1, x2, x3;
        ld4bf(h1 + (size_t)r * HID + f, x0, x1, x2, x3);
        a0 += cw * x0; a1 += cw * x1; a2 += cw * x2; a3 += cw * x3;
    }
    float x0, x1, x2, x3;
    ld4bf(h1 + (size_t)n * HID + f, x0, x1, x2, x3);
    float s = dn * dn;
    float4 o;
    o.x = fmaxf(dn * a0 + s * x0 + ldf(b1, f + 0, f32), 0.f);
    o.y = fmaxf(dn * a1 + s * x1 + ldf(b1, f + 1, f32), 0.f);
    o.z = fmaxf(dn * a2 + s * x2 + ldf(b1, f + 2, f32), 0.f);
    o.w = fmaxf(dn * a3 + s * x3 + ldf(b1, f + 3, f32), 0.f);
    *(float4*)(out1 + (size_t)n * HID + f) = o;
}

// ---- K7: h2 = out1 @ W2 ----
__global__ __launch_bounds__(256) void k_gemm2(const float* __restrict__ out1,
                                               const void* __restrict__ W2,
                                               const Flags* __restrict__ fl,
                                               float* __restrict__ h2) {
    __shared__ float Ws[HID * COUT];  // 4 KB
    int t = threadIdx.x;
    int f32 = fl->f32;
    for (int i = t; i < HID * COUT; i += 256) Ws[i] = ldf(W2, i, f32);
    __syncthreads();
    int node = blockIdx.x * 64 + (t >> 2);  // 64 nodes/block, 4 threads/node
    if (node >= NN) return;
    int o4 = (t & 3) * 4;
    const float* xr = out1 + (size_t)node * HID;
    float a0 = 0.f, a1 = 0.f, a2 = 0.f, a3 = 0.f;
#pragma unroll 4
    for (int k = 0; k < HID; ++k) {
        float xv = xr[k];
        const float* wr = &Ws[k * COUT + o4];
        a0 += xv * wr[0]; a1 += xv * wr[1]; a2 += xv * wr[2]; a3 += xv * wr[3];
    }
    float* ho = h2 + (size_t)node * COUT + o4;
    ho[0] = a0; ho[1] = a1; ho[2] = a2; ho[3] = a3;
}

// ---- K8: gather-aggregate layer 2 + fused epilogue -> out (fp32 or bf16) ----
__global__ __launch_bounds__(256) void k_agg2(const int* __restrict__ rowptrB,
                                              const int2* __restrict__ epack,
                                              const float* __restrict__ dinv2,
                                              const float* __restrict__ h2,
                                              const void* __restrict__ bias2,
                                              const Flags* __restrict__ fl,
                                              const int* __restrict__ delpos,
                                              void* __restrict__ out) {
    int t = threadIdx.x;
    int n = blockIdx.x * 64 + (t >> 2);  // 64 nodes/block, 4 threads/node
    if (n >= NN) return;
    int f = (t & 3) * 4;
    int f32 = fl->f32;
    int dp = *delpos;
    float dn = dinv2[n];
    int p0 = rowptrB[(size_t)n * NC], p1 = rowptrB[(size_t)(n + 1) * NC];
    float a0 = 0.f, a1 = 0.f, a2 = 0.f, a3 = 0.f;
    for (int p = p0; p < p1; ++p) {
        int2 ev = epack[p];
        int r = ev.x;
        float w = (p == dp) ? 0.f : __int_as_float(ev.y);
        float cw = dinv2[r] * w;
        const float4 hv = *(const float4*)(h2 + (size_t)r * COUT + f);
        a0 += cw * hv.x; a1 += cw * hv.y; a2 += cw * hv.z; a3 += cw * hv.w;
    }
    float s = dn * dn;
    const float4 hn = *(const float4*)(h2 + (size_t)n * COUT + f);
    float o0 = dn * a0 + s * hn.x + ldf(bias2, f + 0, f32);
    float o1 = dn * a1 + s * hn.y + ldf(bias2, f + 1, f32);
    float o2 = dn * a2 + s * hn.z + ldf(bias2, f + 2, f32);
    float o3 = dn * a3 + s * hn.w + ldf(bias2, f + 3, f32);
    size_t idx = (size_t)n * COUT + f;
    if (f32) {
        float* op = (float*)out + idx;
        op[0] = o0; op[1] = o1; op[2] = o2; op[3] = o3;
    } else {
        union { uint2 u; __hip_bfloat16 h[4]; } pk;
        pk.h[0] = __float2bfloat16(o0); pk.h[1] = __float2bfloat16(o1);
        pk.h[2] = __float2bfloat16(o2); pk.h[3] = __float2bfloat16(o3);
        *(uint2*)((__hip_bfloat16*)out + idx) = pk.u;
    }
}

extern "C" void kernel_launch(void* const* d_in, const int* in_sizes, int n_in,
                              void* d_out, int out_size, void* d_ws, size_t ws_size,
                              hipStream_t stream) {
    const void* x  = d_in[0];
    const void* ei = d_in[1];
    const void* ew = d_in[2];
    const void* W1 = d_in[3];
    const void* b1 = d_in[4];
    const void* W2 = d_in[5];
    const void* b2 = d_in[6];

    // workspace layout: ~64.8 MB (h2 aliases hist8: hist8 dead after dinv/scanA,
    // h2 first written by k_gemm2 much later — safe on a single stream)
    char* wsb = (char*)d_ws;
    float* dinv1   = (float*)wsb;                      wsb += (size_t)NN * 4;
    float* dinv2   = (float*)wsb;                      wsb += (size_t)NN * 4;
    int*   rowptrB = (int*)wsb;                        wsb += (size_t)(NBINS + 1) * 4;
    int*   cursorB = (int*)wsb;                        wsb += (size_t)NBINS * 4;
    int*   blocksum= (int*)wsb;                        wsb += (size_t)SCAN_NB * 4;
    int*   blockoff= (int*)wsb;                        wsb += (size_t)SCAN_NB * 4;
    wsb = (char*)(((uintptr_t)wsb + 15) & ~(uintptr_t)15);
    u64*   hist8   = (u64*)wsb;                        // NBINS u64 = 6.4 MB ...
    float* h2      = (float*)wsb;                      wsb += (size_t)NBINS * 8;  // aliased (h2 = 6.4 MB too)
    int2*  epack   = (int2*)wsb;                       wsb += (size_t)NE * 8;
    __hip_bfloat16* h1 = (__hip_bfloat16*)wsb;         wsb += (size_t)NN * HID * 2;
    float* out1    = (float*)wsb;                      wsb += (size_t)NN * HID * 4;
    u64*   minkey  = (u64*)wsb;                        wsb += 8;
    Flags* fl      = (Flags*)wsb;                      wsb += 8;
    int*   delpos  = (int*)wsb;                        wsb += 8;

    hipMemsetAsync(hist8,   0, (size_t)NBINS * 8, stream);
    hipMemsetAsync(cursorB, 0, (size_t)NBINS * 4, stream);
    hipMemsetAsync(minkey, 0xFF, 8, stream);
    hipMemsetAsync(delpos, 0xFF, 4, stream);

    k_detect<<<1, 64, 0, stream>>>((const unsigned short*)x, (const int*)ei, fl);
    k_hist<<<(NE + 255) / 256, 256, 0, stream>>>(ei, ew, fl, hist8, minkey);
    k_dinv<<<(NN + 255) / 256, 256, 0, stream>>>(hist8, ei, ew, fl, minkey, dinv1, dinv2);
    k_scanA<<<SCAN_NB, SCAN_T, 0, stream>>>(hist8, rowptrB, blocksum);
    k_scanB<<<1, 1024, 0, stream>>>(blocksum, blockoff, rowptrB);
    k_scanC<<<SCAN_NB, SCAN_T, 0, stream>>>(blockoff, rowptrB);
    k_place<<<(NE + 255) / 256, 256, 0, stream>>>(ei, ew, fl, minkey, rowptrB, cursorB,
                                                  epack, delpos);
    k_gemm1<<<(NN + 15) / 16, 256, 0, stream>>>(x, W1, fl, h1);
    k_agg1<<<(NN + 15) / 16, 256, 0, stream>>>(rowptrB, epack, dinv1, h1, b1, fl, out1);
    k_gemm2<<<(NN + 63) / 64, 256, 0, stream>>>(out1, W2, fl, h2);
    k_agg2<<<(NN + 63) / 64, 256, 0, stream>>>(rowptrB, epack, dinv2, h2, b2, fl,
                                               delpos, d_out);
}

// Round 6
// 478.709 us; speedup vs baseline: 4.0922x; 1.1240x over previous
//
#include <hip/hip_runtime.h>
#include <hip/hip_bf16.h>
#include <stdint.h>

#define NN 100000
#define NE 1600000
#define FIN 128
#define HID 64
#define COUT 16

#define NC 8                    // colors (sub-bins per node)
#define NBINS (NN * NC)         // 800000
#define SC 4                    // bins per thread in scan
#define SCAN_T 256
#define SCAN_SPAN (SCAN_T * SC) // 1024 bins per scan block
#define SCAN_NB ((NBINS + SCAN_SPAN - 1) / SCAN_SPAN)  // 782

#define MASK44 ((1ull << 44) - 1)

typedef unsigned long long u64;
typedef short bf16x8 __attribute__((ext_vector_type(8)));   // 8 bf16 in 4 VGPRs
typedef float f32x4 __attribute__((ext_vector_type(4)));

struct Flags { int f32; int i64; };

__device__ __forceinline__ float b2f(__hip_bfloat16 v) { return __bfloat162float(v); }

// adaptive float load: fp32 buffer or bf16 buffer
__device__ __forceinline__ float ldf(const void* p, size_t i, int f32) {
    return f32 ? ((const float*)p)[i]
               : __bfloat162float(((const __hip_bfloat16*)p)[i]);
}
// adaptive edge-index load: int32 or int64 buffer, logical index i in [0, 2*NE)
__device__ __forceinline__ int lde(const void* p, size_t i, int i64) {
    return i64 ? (int)((const long long*)p)[i] : ((const int*)p)[i];
}
// load 4 consecutive bf16 (8B-aligned) -> 4 floats
__device__ __forceinline__ void ld4bf(const __hip_bfloat16* p, float& x0, float& x1,
                                      float& x2, float& x3) {
    union { uint2 u; __hip_bfloat16 h[4]; } v;
    v.u = *(const uint2*)p;
    x0 = b2f(v.h[0]); x1 = b2f(v.h[1]); x2 = b2f(v.h[2]); x3 = b2f(v.h[3]);
}

// ---- K0: detect input dtypes on-device (one wave + ballot) ----
__global__ void k_detect(const unsigned short* xs, const int* ei32, Flags* fl) {
    int lane = threadIdx.x & 63;
    int huge = 0;
    for (int i = lane * 2; i < 1024; i += 128) {          // even 16-bit words of x
        int e = (xs[i] >> 7) & 0xFF;
        if (e >= 0xC0) huge = 1;   // fp32 low-halves have random exponents; bf16 N(0,1) never
    }
    int odd_nonzero = 0;
    for (int i = 1 + lane * 2; i < 512; i += 128) {       // odd int32 words of edge_index
        if (ei32[i] != 0) odd_nonzero = 1;                // int64 high words are all 0
    }
    u64 h = __ballot(huge), o = __ballot(odd_nonzero);
    if (lane == 0) { fl->f32 = (h != 0); fl->i64 = (o == 0); }
}

// ---- K1: packed per-(node,color) histogram: count<<44 | fixed-point weight sum ----
__global__ void k_hist(const void* __restrict__ ei, const void* __restrict__ ew,
                       const Flags* __restrict__ fl,
                       u64* __restrict__ hist8, u64* __restrict__ minkey) {
    int e = blockIdx.x * blockDim.x + threadIdx.x;
    if (e >= NE) return;
    int color = blockIdx.x & (NC - 1);
    int f32 = fl->f32, i64 = fl->i64;
    int r = lde(ei, e, i64);
    int c = lde(ei, (size_t)NE + e, i64);
    float w = ldf(ew, e, f32);
    // w in [0,1]: w*2^32 exact in double (24-bit mantissa), < 2^33 << 2^44
    u64 add = (1ull << 44) | (u64)((double)w * 4294967296.0);
    atomicAdd(&hist8[(size_t)c * NC + color], add);
    if (r == 0) {
        u64 key = ((u64)__float_as_uint(w) << 32) | (unsigned)e;  // w>=0: bits monotone
        atomicMin(minkey, key);
    }
}

// ---- K2: dinv for both layers (deg recovered from fixed-point bins; exact) ----
__global__ void k_dinv(const u64* __restrict__ hist8, const void* __restrict__ ei,
                       const void* __restrict__ ew, const Flags* __restrict__ fl,
                       const u64* __restrict__ minkey,
                       float* __restrict__ dinv1, float* __restrict__ dinv2) {
    int i = blockIdx.x * blockDim.x + threadIdx.x;
    if (i >= NN) return;
    int f32 = fl->f32, i64 = fl->i64;
    u64 wsum = 0;
#pragma unroll
    for (int c = 0; c < NC; ++c) wsum += hist8[(size_t)i * NC + c] & MASK44;
    float deg = (float)((double)wsum * (1.0 / 4294967296.0));
    u64 k = *minkey;
    int eidx = (k == ~0ull) ? 0 : (int)(k & 0xffffffffu);  // argmin(all-inf)==0, like jnp
    int cmin = lde(ei, (size_t)NE + eidx, i64);
    float wmin = ldf(ew, eidx, f32);
    float d1 = deg + 1.0f;                    // +1 for self loop
    float d2 = d1 - ((i == cmin) ? wmin : 0.0f);
    dinv1[i] = rsqrtf(d1);
    dinv2[i] = rsqrtf(d2);
}

// ---- K3a: per-block local exclusive scan of bin counts ----
__global__ __launch_bounds__(SCAN_T) void k_scanA(const u64* __restrict__ hist8,
                                                  int* __restrict__ rowptrB,
                                                  int* __restrict__ blocksum) {
    __shared__ int sm[SCAN_T];
    int b = blockIdx.x, t = threadIdx.x;
    int base = b * SCAN_SPAN + t * SC;
    int v[SC];
    int s = 0;
#pragma unroll
    for (int j = 0; j < SC; ++j) {
        int idx = base + j;
        v[j] = (idx < NBINS) ? (int)(hist8[idx] >> 44) : 0;
        s += v[j];
    }
    sm[t] = s;
    for (int off = 1; off < SCAN_T; off <<= 1) {
        __syncthreads();
        int add = (t >= off) ? sm[t - off] : 0;
        __syncthreads();
        sm[t] += add;
    }
    __syncthreads();
    int run = sm[t] - s;  // exclusive prefix within block
#pragma unroll
    for (int j = 0; j < SC; ++j) {
        int idx = base + j;
        if (idx < NBINS) rowptrB[idx] = run;
        run += v[j];
    }
    if (t == SCAN_T - 1) blocksum[b] = sm[SCAN_T - 1];
}

// ---- K3b: scan the block sums (1 block, 1024 threads) ----
__global__ __launch_bounds__(1024) void k_scanB(const int* __restrict__ blocksum,
                                                int* __restrict__ blockoff,
                                                int* __restrict__ rowptrB) {
    __shared__ int sm[1024];
    int t = threadIdx.x;
    int v = (t < SCAN_NB) ? blocksum[t] : 0;
    sm[t] = v;
    for (int off = 1; off < 1024; off <<= 1) {
        __syncthreads();
        int add = (t >= off) ? sm[t - off] : 0;
        __syncthreads();
        sm[t] += add;
    }
    __syncthreads();
    if (t < SCAN_NB) blockoff[t] = sm[t] - v;     // exclusive block offset
    if (t == 1023) rowptrB[NBINS] = sm[1023];     // == NE
}

// ---- K3c: add block offsets ----
__global__ __launch_bounds__(SCAN_T) void k_scanC(const int* __restrict__ blockoff,
                                                  int* __restrict__ rowptrB) {
    int b = blockIdx.x, t = threadIdx.x;
    int base = b * SCAN_SPAN + t * SC;
    int off = blockoff[b];
#pragma unroll
    for (int j = 0; j < SC; ++j) {
        int idx = base + j;
        if (idx < NBINS) rowptrB[idx] += off;
    }
}

// ---- K4: placement — counting sort by (dest,color) bin, packed (src,w) ----
__global__ void k_place(const void* __restrict__ ei, const void* __restrict__ ew,
                        const Flags* __restrict__ fl, const u64* __restrict__ minkey,
                        const int* __restrict__ rowptrB, int* __restrict__ cursorB,
                        int2* __restrict__ epack, int* __restrict__ delpos) {
    int e = blockIdx.x * blockDim.x + threadIdx.x;
    if (e >= NE) return;
    int color = blockIdx.x & (NC - 1);   // MUST match k_hist's color formula
    int f32 = fl->f32, i64 = fl->i64;
    int r = lde(ei, e, i64);
    int c = lde(ei, (size_t)NE + e, i64);
    float w = ldf(ew, e, f32);
    int bin = c * NC + color;
    int pos = rowptrB[bin] + atomicAdd(&cursorB[bin], 1);
    epack[pos] = make_int2(r, __float_as_int(w));
    u64 k = *minkey;
    int eidx = (k == ~0ull) ? 0 : (int)(k & 0xffffffffu);
    if (e == eidx) *delpos = pos;
}

// ---- K5-MFMA: h1 = x @ W1 (bf16 inputs path) ----
// wave tile: 16 nodes x 64 cols, K=128 in 4 chunks of 32 via v_mfma_f32_16x16x32_bf16.
// A[m=lane&15][k=quad*8+j] straight from x; B pre-swizzled in LDS for ds_read_b128.
__global__ __launch_bounds__(256) void k_gemm1_mfma(const __hip_bfloat16* __restrict__ x,
                                                    const unsigned short* __restrict__ W1,
                                                    const Flags* __restrict__ fl,
                                                    __hip_bfloat16* __restrict__ h1) {
    if (fl->f32) return;   // fp32 path handled by k_gemm1_valu
    __shared__ unsigned short Wf[8192];  // [(n0*4+kc)*4+q][col*8+j]  16 KB
    int t = threadIdx.x;
    for (int i = t; i < 8192; i += 256) {
        int k = i >> 6;                 // 0..127
        int n = i & 63;                 // 0..63
        int kc = k >> 5, kr = k & 31;
        int q = kr >> 3, j = kr & 7;
        int n0 = n >> 4, col = n & 15;
        Wf[((((n0 << 2) | kc) << 2) | q) * 128 + col * 8 + j] = W1[i];
    }
    __syncthreads();
    int wave = t >> 6, lane = t & 63;
    int quad = lane >> 4, col = lane & 15;
    bf16x8 B[4][4];                      // [kc][n0]
#pragma unroll
    for (int n0 = 0; n0 < 4; ++n0)
#pragma unroll
        for (int kc = 0; kc < 4; ++kc)
            B[kc][n0] = *(const bf16x8*)&Wf[((((n0 << 2) | kc) << 2) | quad) * 128 + col * 8];
    int tile0 = (blockIdx.x * 4 + wave) * 4;   // 4 node-tiles of 16 per wave
#pragma unroll 1
    for (int i = 0; i < 4; ++i) {
        int node0 = (tile0 + i) * 16;
        if (node0 >= NN) return;        // NN % 16 == 0: tiles all-valid or all-invalid
        const __hip_bfloat16* xp = x + (size_t)(node0 + col) * FIN + quad * 8;
        f32x4 a0 = {0.f, 0.f, 0.f, 0.f}, a1 = a0, a2 = a0, a3 = a0;
#pragma unroll
        for (int kc = 0; kc < 4; ++kc) {
            bf16x8 A = *(const bf16x8*)(xp + kc * 32);
            a0 = __builtin_amdgcn_mfma_f32_16x16x32_bf16(A, B[kc][0], a0, 0, 0, 0);
            a1 = __builtin_amdgcn_mfma_f32_16x16x32_bf16(A, B[kc][1], a1, 0, 0, 0);
            a2 = __builtin_amdgcn_mfma_f32_16x16x32_bf16(A, B[kc][2], a2, 0, 0, 0);
            a3 = __builtin_amdgcn_mfma_f32_16x16x32_bf16(A, B[kc][3], a3, 0, 0, 0);
        }
        // C/D layout: row = quad*4 + reg, col = lane&15 (verified m89/m91)
        __hip_bfloat16* hp = h1 + (size_t)(node0 + quad * 4) * HID + col;
#pragma unroll
        for (int r = 0; r < 4; ++r) {
            hp[(size_t)r * HID + 0]  = __float2bfloat16(a0[r]);
            hp[(size_t)r * HID + 16] = __float2bfloat16(a1[r]);
            hp[(size_t)r * HID + 32] = __float2bfloat16(a2[r]);
            hp[(size_t)r * HID + 48] = __float2bfloat16(a3[r]);
        }
    }
}

// ---- K5-fallback: fp32-input path (early-exits when inputs are bf16) ----
__global__ __launch_bounds__(256) void k_gemm1_valu(const void* __restrict__ x,
                                                    const void* __restrict__ W1,
                                                    const Flags* __restrict__ fl,
                                                    __hip_bfloat16* __restrict__ h1) {
    if (!fl->f32) return;  // bf16 path handled by k_gemm1_mfma
    __shared__ float Ws[FIN * HID];  // 32 KB
    int t = threadIdx.x;
    for (int i = t; i < FIN * HID; i += 256) Ws[i] = ((const float*)W1)[i];
    __syncthreads();
    int node = blockIdx.x * 16 + (t >> 4);
    if (node >= NN) return;
    int o4 = (t & 15) * 4;
    const float* xr = (const float*)x + (size_t)node * FIN;
    float a0 = 0.f, a1 = 0.f, a2 = 0.f, a3 = 0.f;
#pragma unroll 4
    for (int k = 0; k < FIN; ++k) {
        float xv = xr[k];
        const float* wr = &Ws[k * HID + o4];
        a0 += xv * wr[0]; a1 += xv * wr[1]; a2 += xv * wr[2]; a3 += xv * wr[3];
    }
    union { uint2 u; __hip_bfloat16 h[4]; } pk;
    pk.h[0] = __float2bfloat16(a0); pk.h[1] = __float2bfloat16(a1);
    pk.h[2] = __float2bfloat16(a2); pk.h[3] = __float2bfloat16(a3);
    *(uint2*)(h1 + (size_t)node * HID + o4) = pk.u;
}

// ---- K6: gather-aggregate layer 1 + fused epilogue (relu(agg + dinv^2 h + b)) ----
__global__ __launch_bounds__(256) void k_agg1(const int* __restrict__ rowptrB,
                                              const int2* __restrict__ epack,
                                              const float* __restrict__ dinv1,
                                              const __hip_bfloat16* __restrict__ h1,
                                              const void* __restrict__ b1,
                                              const Flags* __restrict__ fl,
                                              float* __restrict__ out1) {
    int t = threadIdx.x;
    int n = blockIdx.x * 16 + (t >> 4);  // 16 nodes/block, 16 threads/node
    if (n >= NN) return;
    int f = (t & 15) * 4;
    int f32 = fl->f32;
    float dn = dinv1[n];
    int p0 = rowptrB[(size_t)n * NC], p1 = rowptrB[(size_t)(n + 1) * NC];
    float a0 = 0.f, a1 = 0.f, a2 = 0.f, a3 = 0.f;
    for (int p = p0; p < p1; ++p) {
        int2 ev = epack[p];
        int r = ev.x;
        float cw = dinv1[r] * __int_as_float(ev.y);
        float x0, x1, x2, x3;
        ld4bf(h1 + (size_t)r * HID + f, x0, x1, x2, x3);
        a0 += cw * x0; a1 += cw * x1; a2 += cw * x2; a3 += cw * x3;
    }
    float x0, x1, x2, x3;
    ld4bf(h1 + (size_t)n * HID + f, x0, x1, x2, x3);
    float s = dn * dn;
    float4 o;
    o.x = fmaxf(dn * a0 + s * x0 + ldf(b1, f + 0, f32), 0.f);
    o.y = fmaxf(dn * a1 + s * x1 + ldf(b1, f + 1, f32), 0.f);
    o.z = fmaxf(dn * a2 + s * x2 + ldf(b1, f + 2, f32), 0.f);
    o.w = fmaxf(dn * a3 + s * x3 + ldf(b1, f + 3, f32), 0.f);
    *(float4*)(out1 + (size_t)n * HID + f) = o;
}

// ---- K7: h2 = out1 @ W2 ----
__global__ __launch_bounds__(256) void k_gemm2(const float* __restrict__ out1,
                                               const void* __restrict__ W2,
                                               const Flags* __restrict__ fl,
                                               float* __restrict__ h2) {
    __shared__ float Ws[HID * COUT];  // 4 KB
    int t = threadIdx.x;
    int f32 = fl->f32;
    for (int i = t; i < HID * COUT; i += 256) Ws[i] = ldf(W2, i, f32);
    __syncthreads();
    int node = blockIdx.x * 64 + (t >> 2);  // 64 nodes/block, 4 threads/node
    if (node >= NN) return;
    int o4 = (t & 3) * 4;
    const float* xr = out1 + (size_t)node * HID;
    float a0 = 0.f, a1 = 0.f, a2 = 0.f, a3 = 0.f;
#pragma unroll 4
    for (int k = 0; k < HID; ++k) {
        float xv = xr[k];
        const float* wr = &Ws[k * COUT + o4];
        a0 += xv * wr[0]; a1 += xv * wr[1]; a2 += xv * wr[2]; a3 += xv * wr[3];
    }
    float* ho = h2 + (size_t)node * COUT + o4;
    ho[0] = a0; ho[1] = a1; ho[2] = a2; ho[3] = a3;
}

// ---- K8: gather-aggregate layer 2 + fused epilogue -> out (fp32 or bf16) ----
__global__ __launch_bounds__(256) void k_agg2(const int* __restrict__ rowptrB,
                                              const int2* __restrict__ epack,
                                              const float* __restrict__ dinv2,
                                              const float* __restrict__ h2,
                                              const void* __restrict__ bias2,
                                              const Flags* __restrict__ fl,
                                              const int* __restrict__ delpos,
                                              void* __restrict__ out) {
    int t = threadIdx.x;
    int n = blockIdx.x * 64 + (t >> 2);  // 64 nodes/block, 4 threads/node
    if (n >= NN) return;
    int f = (t & 3) * 4;
    int f32 = fl->f32;
    int dp = *delpos;
    float dn = dinv2[n];
    int p0 = rowptrB[(size_t)n * NC], p1 = rowptrB[(size_t)(n + 1) * NC];
    float a0 = 0.f, a1 = 0.f, a2 = 0.f, a3 = 0.f;
    for (int p = p0; p < p1; ++p) {
        int2 ev = epack[p];
        int r = ev.x;
        float w = (p == dp) ? 0.f : __int_as_float(ev.y);
        float cw = dinv2[r] * w;
        const float4 hv = *(const float4*)(h2 + (size_t)r * COUT + f);
        a0 += cw * hv.x; a1 += cw * hv.y; a2 += cw * hv.z; a3 += cw * hv.w;
    }
    float s = dn * dn;
    const float4 hn = *(const float4*)(h2 + (size_t)n * COUT + f);
    float o0 = dn * a0 + s * hn.x + ldf(bias2, f + 0, f32);
    float o1 = dn * a1 + s * hn.y + ldf(bias2, f + 1, f32);
    float o2 = dn * a2 + s * hn.z + ldf(bias2, f + 2, f32);
    float o3 = dn * a3 + s * hn.w + ldf(bias2, f + 3, f32);
    size_t idx = (size_t)n * COUT + f;
    if (f32) {
        float* op = (float*)out + idx;
        op[0] = o0; op[1] = o1; op[2] = o2; op[3] = o3;
    } else {
        union { uint2 u; __hip_bfloat16 h[4]; } pk;
        pk.h[0] = __float2bfloat16(o0); pk.h[1] = __float2bfloat16(o1);
        pk.h[2] = __float2bfloat16(o2); pk.h[3] = __float2bfloat16(o3);
        *(uint2*)((__hip_bfloat16*)out + idx) = pk.u;
    }
}

extern "C" void kernel_launch(void* const* d_in, const int* in_sizes, int n_in,
                              void* d_out, int out_size, void* d_ws, size_t ws_size,
                              hipStream_t stream) {
    const void* x  = d_in[0];
    const void* ei = d_in[1];
    const void* ew = d_in[2];
    const void* W1 = d_in[3];
    const void* b1 = d_in[4];
    const void* W2 = d_in[5];
    const void* b2 = d_in[6];

    // workspace layout: ~64.8 MB (h2 aliases hist8: hist8 dead after dinv/scanA,
    // h2 first written by k_gemm2 much later — safe on a single stream)
    char* wsb = (char*)d_ws;
    float* dinv1   = (float*)wsb;                      wsb += (size_t)NN * 4;
    float* dinv2   = (float*)wsb;                      wsb += (size_t)NN * 4;
    int*   rowptrB = (int*)wsb;                        wsb += (size_t)(NBINS + 1) * 4;
    int*   cursorB = (int*)wsb;                        wsb += (size_t)NBINS * 4;
    int*   blocksum= (int*)wsb;                        wsb += (size_t)SCAN_NB * 4;
    int*   blockoff= (int*)wsb;                        wsb += (size_t)SCAN_NB * 4;
    wsb = (char*)(((uintptr_t)wsb + 15) & ~(uintptr_t)15);
    u64*   hist8   = (u64*)wsb;                        // NBINS u64 = 6.4 MB ...
    float* h2      = (float*)wsb;                      wsb += (size_t)NBINS * 8;  // aliased (h2 = 6.4 MB too)
    int2*  epack   = (int2*)wsb;                       wsb += (size_t)NE * 8;
    __hip_bfloat16* h1 = (__hip_bfloat16*)wsb;         wsb += (size_t)NN * HID * 2;
    float* out1    = (float*)wsb;                      wsb += (size_t)NN * HID * 4;
    u64*   minkey  = (u64*)wsb;                        wsb += 8;
    Flags* fl      = (Flags*)wsb;                      wsb += 8;
    int*   delpos  = (int*)wsb;                        wsb += 8;

    hipMemsetAsync(hist8,   0, (size_t)NBINS * 8, stream);
    hipMemsetAsync(cursorB, 0, (size_t)NBINS * 4, stream);
    hipMemsetAsync(minkey, 0xFF, 8, stream);
    hipMemsetAsync(delpos, 0xFF, 4, stream);

    k_detect<<<1, 64, 0, stream>>>((const unsigned short*)x, (const int*)ei, fl);
    k_hist<<<(NE + 255) / 256, 256, 0, stream>>>(ei, ew, fl, hist8, minkey);
    k_dinv<<<(NN + 255) / 256, 256, 0, stream>>>(hist8, ei, ew, fl, minkey, dinv1, dinv2);
    k_scanA<<<SCAN_NB, SCAN_T, 0, stream>>>(hist8, rowptrB, blocksum);
    k_scanB<<<1, 1024, 0, stream>>>(blocksum, blockoff, rowptrB);
    k_scanC<<<SCAN_NB, SCAN_T, 0, stream>>>(blockoff, rowptrB);
    k_place<<<(NE + 255) / 256, 256, 0, stream>>>(ei, ew, fl, minkey, rowptrB, cursorB,
                                                  epack, delpos);
    // 6250 node-tiles of 16; 16 tiles per block (4 waves x 4) -> 391 blocks
    k_gemm1_mfma<<<(NN / 16 + 15) / 16, 256, 0, stream>>>((const __hip_bfloat16*)x,
                                                          (const unsigned short*)W1, fl,
                                                          (__hip_bfloat16*)h1);
    k_gemm1_valu<<<(NN + 15) / 16, 256, 0, stream>>>(x, W1, fl, h1);
    k_agg1<<<(NN + 15) / 16, 256, 0, stream>>>(rowptrB, epack, dinv1, h1, b1, fl, out1);
    k_gemm2<<<(NN + 63) / 64, 256, 0, stream>>>(out1, W2, fl, h2);
    k_agg2<<<(NN + 63) / 64, 256, 0, stream>>>(rowptrB, epack, dinv2, h2, b2, fl,
                                               delpos, d_out);
}

// Round 8
// 419.901 us; speedup vs baseline: 4.6654x; 1.1401x over previous
//
#include <hip/hip_runtime.h>
#include <hip/hip_bf16.h>
#include <stdint.h>

#define NN 100000
#define NE 1600000
#define FIN 128
#define HID 64
#define COUT 16

#define NC 8                    // colors (sub-bins per node)
#define NBINS (NN * NC)         // 800000
#define SC 4                    // bins per thread in scan
#define SCAN_T 256
#define SCAN_SPAN (SCAN_T * SC) // 1024 bins per scan block
#define SCAN_NB ((NBINS + SCAN_SPAN - 1) / SCAN_SPAN)  // 782

#define MASK44 ((1ull << 44) - 1)

typedef unsigned long long u64;
typedef short bf16x8 __attribute__((ext_vector_type(8)));   // 8 bf16 in 4 VGPRs
typedef float f32x4 __attribute__((ext_vector_type(4)));

struct Flags { int f32; int i64; };

__device__ __forceinline__ float b2f(__hip_bfloat16 v) { return __bfloat162float(v); }

// adaptive float load: fp32 buffer or bf16 buffer
__device__ __forceinline__ float ldf(const void* p, size_t i, int f32) {
    return f32 ? ((const float*)p)[i]
               : __bfloat162float(((const __hip_bfloat16*)p)[i]);
}
// adaptive edge-index load: int32 or int64 buffer, logical index i in [0, 2*NE)
__device__ __forceinline__ int lde(const void* p, size_t i, int i64) {
    return i64 ? (int)((const long long*)p)[i] : ((const int*)p)[i];
}
// load 4 consecutive bf16 (8B-aligned) -> 4 floats
__device__ __forceinline__ void ld4bf(const __hip_bfloat16* p, float& x0, float& x1,
                                      float& x2, float& x3) {
    union { uint2 u; __hip_bfloat16 h[4]; } v;
    v.u = *(const uint2*)p;
    x0 = b2f(v.h[0]); x1 = b2f(v.h[1]); x2 = b2f(v.h[2]); x3 = b2f(v.h[3]);
}

// ---- K0: detect input dtypes on-device (one wave + ballot) ----
__global__ void k_detect(const unsigned short* xs, const int* ei32, Flags* fl) {
    int lane = threadIdx.x & 63;
    int huge = 0;
    for (int i = lane * 2; i < 1024; i += 128) {          // even 16-bit words of x
        int e = (xs[i] >> 7) & 0xFF;
        if (e >= 0xC0) huge = 1;   // fp32 low-halves have random exponents; bf16 N(0,1) never
    }
    int odd_nonzero = 0;
    for (int i = 1 + lane * 2; i < 512; i += 128) {       // odd int32 words of edge_index
        if (ei32[i] != 0) odd_nonzero = 1;                // int64 high words are all 0
    }
    u64 h = __ballot(huge), o = __ballot(odd_nonzero);
    if (lane == 0) { fl->f32 = (h != 0); fl->i64 = (o == 0); }
}

// ---- K1: packed per-(node,color) histogram: count<<44 | fixed-point weight sum ----
__global__ void k_hist(const void* __restrict__ ei, const void* __restrict__ ew,
                       const Flags* __restrict__ fl,
                       u64* __restrict__ hist8, u64* __restrict__ minkey) {
    int e = blockIdx.x * blockDim.x + threadIdx.x;
    if (e >= NE) return;
    int color = blockIdx.x & (NC - 1);
    int f32 = fl->f32, i64 = fl->i64;
    int r = lde(ei, e, i64);
    int c = lde(ei, (size_t)NE + e, i64);
    float w = ldf(ew, e, f32);
    // w in [0,1]: w*2^32 exact in double (24-bit mantissa), < 2^33 << 2^44
    u64 add = (1ull << 44) | (u64)((double)w * 4294967296.0);
    atomicAdd(&hist8[(size_t)c * NC + color], add);
    if (r == 0) {
        u64 key = ((u64)__float_as_uint(w) << 32) | (unsigned)e;  // w>=0: bits monotone
        atomicMin(minkey, key);
    }
}

// ---- K2: dinv for both layers (deg recovered from fixed-point bins; exact) ----
__global__ void k_dinv(const u64* __restrict__ hist8, const void* __restrict__ ei,
                       const void* __restrict__ ew, const Flags* __restrict__ fl,
                       const u64* __restrict__ minkey,
                       float* __restrict__ dinv1, float* __restrict__ dinv2) {
    int i = blockIdx.x * blockDim.x + threadIdx.x;
    if (i >= NN) return;
    int f32 = fl->f32, i64 = fl->i64;
    u64 wsum = 0;
#pragma unroll
    for (int c = 0; c < NC; ++c) wsum += hist8[(size_t)i * NC + c] & MASK44;
    float deg = (float)((double)wsum * (1.0 / 4294967296.0));
    u64 k = *minkey;
    int eidx = (k == ~0ull) ? 0 : (int)(k & 0xffffffffu);  // argmin(all-inf)==0, like jnp
    int cmin = lde(ei, (size_t)NE + eidx, i64);
    float wmin = ldf(ew, eidx, f32);
    float d1 = deg + 1.0f;                    // +1 for self loop
    float d2 = d1 - ((i == cmin) ? wmin : 0.0f);
    dinv1[i] = rsqrtf(d1);
    dinv2[i] = rsqrtf(d2);
}

// ---- K3a: per-block local exclusive scan of bin counts ----
__global__ __launch_bounds__(SCAN_T) void k_scanA(const u64* __restrict__ hist8,
                                                  int* __restrict__ rowptrB,
                                                  int* __restrict__ blocksum) {
    __shared__ int sm[SCAN_T];
    int b = blockIdx.x, t = threadIdx.x;
    int base = b * SCAN_SPAN + t * SC;
    int v[SC];
    int s = 0;
#pragma unroll
    for (int j = 0; j < SC; ++j) {
        int idx = base + j;
        v[j] = (idx < NBINS) ? (int)(hist8[idx] >> 44) : 0;
        s += v[j];
    }
    sm[t] = s;
    for (int off = 1; off < SCAN_T; off <<= 1) {
        __syncthreads();
        int add = (t >= off) ? sm[t - off] : 0;
        __syncthreads();
        sm[t] += add;
    }
    __syncthreads();
    int run = sm[t] - s;  // exclusive prefix within block
#pragma unroll
    for (int j = 0; j < SC; ++j) {
        int idx = base + j;
        if (idx < NBINS) rowptrB[idx] = run;
        run += v[j];
    }
    if (t == SCAN_T - 1) blocksum[b] = sm[SCAN_T - 1];
}

// ---- K3b: scan the block sums (1 block, 1024 threads) ----
__global__ __launch_bounds__(1024) void k_scanB(const int* __restrict__ blocksum,
                                                int* __restrict__ blockoff,
                                                int* __restrict__ rowptrB) {
    __shared__ int sm[1024];
    int t = threadIdx.x;
    int v = (t < SCAN_NB) ? blocksum[t] : 0;
    sm[t] = v;
    for (int off = 1; off < 1024; off <<= 1) {
        __syncthreads();
        int add = (t >= off) ? sm[t - off] : 0;
        __syncthreads();
        sm[t] += add;
    }
    __syncthreads();
    if (t < SCAN_NB) blockoff[t] = sm[t] - v;     // exclusive block offset
    if (t == 1023) rowptrB[NBINS] = sm[1023];     // == NE
}

// ---- K3c: add block offsets ----
__global__ __launch_bounds__(SCAN_T) void k_scanC(const int* __restrict__ blockoff,
                                                  int* __restrict__ rowptrB) {
    int b = blockIdx.x, t = threadIdx.x;
    int base = b * SCAN_SPAN + t * SC;
    int off = blockoff[b];
#pragma unroll
    for (int j = 0; j < SC; ++j) {
        int idx = base + j;
        if (idx < NBINS) rowptrB[idx] += off;
    }
}

// ---- K4: placement — counting sort by (dest,color) bin, packed (src,w) ----
__global__ void k_place(const void* __restrict__ ei, const void* __restrict__ ew,
                        const Flags* __restrict__ fl, const u64* __restrict__ minkey,
                        const int* __restrict__ rowptrB, int* __restrict__ cursorB,
                        int2* __restrict__ epack, int* __restrict__ delpos) {
    int e = blockIdx.x * blockDim.x + threadIdx.x;
    if (e >= NE) return;
    int color = blockIdx.x & (NC - 1);   // MUST match k_hist's color formula
    int f32 = fl->f32, i64 = fl->i64;
    int r = lde(ei, e, i64);
    int c = lde(ei, (size_t)NE + e, i64);
    float w = ldf(ew, e, f32);
    int bin = c * NC + color;
    int pos = rowptrB[bin] + atomicAdd(&cursorB[bin], 1);
    epack[pos] = make_int2(r, __float_as_int(w));
    u64 k = *minkey;
    int eidx = (k == ~0ull) ? 0 : (int)(k & 0xffffffffu);
    if (e == eidx) *delpos = pos;
}

// ---- K5a: fp32 path — LDS-tiled GEMM, 64 nodes x 64 cols per block ----
// ONE shared array, manually partitioned (round-7 bug: split arrays got
// reordered/eliminated by the LDS allocator — never assume adjacency).
__global__ __launch_bounds__(256) void k_gemm1_f32(const float* __restrict__ x,
                                                   const float* __restrict__ W1,
                                                   const Flags* __restrict__ fl,
                                                   __hip_bfloat16* __restrict__ h1) {
    if (!fl->f32) return;   // bf16 path handled by k_gemm1_mfma
    __shared__ float smem[16384];        // 64 KB: [0,8192)=W1, [8192,16384)=x tile
    float* Wp = smem;
    float* Xs = smem + 8192;
    int t = threadIdx.x;
    int node0 = blockIdx.x * 64;
    {   // stage W1 (8192 floats, float4)
        const float4* src = (const float4*)W1;
        float4* dst = (float4*)Wp;
        for (int i = t; i < 2048; i += 256) dst[i] = src[i];
    }
    {   // stage x tile (rows node0..node0+63 contiguous = 8192 floats)
        int xlim = (NN - node0) * (FIN / 4);           // valid float4 count
        if (xlim > 2048) xlim = 2048;
        const float4* src = (const float4*)(x + (size_t)node0 * FIN);
        float4* dst = (float4*)Xs;
        for (int i = t; i < xlim; i += 256) dst[i] = src[i];
    }
    __syncthreads();
    int col4 = (t & 15) * 4;
    int nb = t >> 4;                                   // 0..15
    float4 a0 = {0,0,0,0}, a1 = a0, a2 = a0, a3 = a0;
#pragma unroll 8
    for (int k = 0; k < FIN; k += 4) {
        float4 w0 = *(const float4*)&Wp[(k + 0) * HID + col4];
        float4 w1 = *(const float4*)&Wp[(k + 1) * HID + col4];
        float4 w2 = *(const float4*)&Wp[(k + 2) * HID + col4];
        float4 w3 = *(const float4*)&Wp[(k + 3) * HID + col4];
        float4 xv;
#define GEMM1_STEP(ACC, NOFF)                                            \
        xv = *(const float4*)&Xs[(nb + NOFF) * FIN + k];                 \
        ACC.x += xv.x * w0.x + xv.y * w1.x + xv.z * w2.x + xv.w * w3.x;  \
        ACC.y += xv.x * w0.y + xv.y * w1.y + xv.z * w2.y + xv.w * w3.y;  \
        ACC.z += xv.x * w0.z + xv.y * w1.z + xv.z * w2.z + xv.w * w3.z;  \
        ACC.w += xv.x * w0.w + xv.y * w1.w + xv.z * w2.w + xv.w * w3.w;
        GEMM1_STEP(a0, 0)
        GEMM1_STEP(a1, 16)
        GEMM1_STEP(a2, 32)
        GEMM1_STEP(a3, 48)
#undef GEMM1_STEP
    }
    float4 accs[4] = {a0, a1, a2, a3};
#pragma unroll
    for (int nn = 0; nn < 4; ++nn) {
        int node = node0 + nb + nn * 16;
        if (node < NN) {
            union { uint2 u; __hip_bfloat16 h[4]; } pk;
            pk.h[0] = __float2bfloat16(accs[nn].x);
            pk.h[1] = __float2bfloat16(accs[nn].y);
            pk.h[2] = __float2bfloat16(accs[nn].z);
            pk.h[3] = __float2bfloat16(accs[nn].w);
            *(uint2*)(h1 + (size_t)node * HID + col4) = pk.u;
        }
    }
}

// ---- K5b: bf16-input path (insurance; exits instantly when inputs are fp32) ----
__global__ __launch_bounds__(256) void k_gemm1_mfma(const __hip_bfloat16* __restrict__ x,
                                                    const unsigned short* __restrict__ W1,
                                                    const Flags* __restrict__ fl,
                                                    __hip_bfloat16* __restrict__ h1) {
    if (fl->f32) return;
    __shared__ unsigned short Wf[8192];  // [(n0*4+kc)*4+q][col*8+j]  16 KB
    int t = threadIdx.x;
    for (int i = t; i < 8192; i += 256) {
        int k = i >> 6;
        int n = i & 63;
        int kc = k >> 5, kr = k & 31;
        int q = kr >> 3, j = kr & 7;
        int n0 = n >> 4, col = n & 15;
        Wf[((((n0 << 2) | kc) << 2) | q) * 128 + col * 8 + j] = W1[i];
    }
    __syncthreads();
    int wave = t >> 6, lane = t & 63;
    int quad = lane >> 4, col = lane & 15;
    bf16x8 B[4][4];
#pragma unroll
    for (int n0 = 0; n0 < 4; ++n0)
#pragma unroll
        for (int kc = 0; kc < 4; ++kc)
            B[kc][n0] = *(const bf16x8*)&Wf[((((n0 << 2) | kc) << 2) | quad) * 128 + col * 8];
    int tile0 = (blockIdx.x * 4 + wave) * 4;
#pragma unroll 1
    for (int i = 0; i < 4; ++i) {
        int node0 = (tile0 + i) * 16;
        if (node0 >= NN) return;
        const __hip_bfloat16* xp = x + (size_t)(node0 + col) * FIN + quad * 8;
        f32x4 a0 = {0.f, 0.f, 0.f, 0.f}, a1 = a0, a2 = a0, a3 = a0;
#pragma unroll
        for (int kc = 0; kc < 4; ++kc) {
            bf16x8 A = *(const bf16x8*)(xp + kc * 32);
            a0 = __builtin_amdgcn_mfma_f32_16x16x32_bf16(A, B[kc][0], a0, 0, 0, 0);
            a1 = __builtin_amdgcn_mfma_f32_16x16x32_bf16(A, B[kc][1], a1, 0, 0, 0);
            a2 = __builtin_amdgcn_mfma_f32_16x16x32_bf16(A, B[kc][2], a2, 0, 0, 0);
            a3 = __builtin_amdgcn_mfma_f32_16x16x32_bf16(A, B[kc][3], a3, 0, 0, 0);
        }
        __hip_bfloat16* hp = h1 + (size_t)(node0 + quad * 4) * HID + col;
#pragma unroll
        for (int r = 0; r < 4; ++r) {
            hp[(size_t)r * HID + 0]  = __float2bfloat16(a0[r]);
            hp[(size_t)r * HID + 16] = __float2bfloat16(a1[r]);
            hp[(size_t)r * HID + 32] = __float2bfloat16(a2[r]);
            hp[(size_t)r * HID + 48] = __float2bfloat16(a3[r]);
        }
    }
}

// ---- K6: gather-aggregate layer 1, shfl-broadcast edge batching ----
// 16-lane group per node: batch-load 16 edges coalesced, broadcast (r,cw) via shfl,
// issue 16 independent h1-row gathers back-to-back (high memory-level parallelism).
// shfl sources always within the group -> uniform exec (whole group shares n,p0,p1).
__global__ __launch_bounds__(256) void k_agg1(const int* __restrict__ rowptrB,
                                              const int2* __restrict__ epack,
                                              const float* __restrict__ dinv1,
                                              const __hip_bfloat16* __restrict__ h1,
                                              const void* __restrict__ b1,
                                              const Flags* __restrict__ fl,
                                              float* __restrict__ out1) {
    int t = threadIdx.x;
    int n = blockIdx.x * 16 + (t >> 4);  // 16 nodes/block, 16 lanes/node
    if (n >= NN) return;
    int l = t & 15;
    int f = l * 4;
    int wbase = t & 48;                  // group base lane within wave
    int f32 = fl->f32;
    float dn = dinv1[n];
    int p0 = rowptrB[(size_t)n * NC], p1 = rowptrB[(size_t)(n + 1) * NC];
    float a0 = 0.f, a1 = 0.f, a2 = 0.f, a3 = 0.f;
    for (int p = p0; p < p1; p += 16) {
        int idx = p + l;
        int2 ev = make_int2(0, 0);
        float cw = 0.f;
        if (idx < p1) {
            ev = epack[idx];                               // coalesced 128 B per group
            cw = dinv1[ev.x] * __int_as_float(ev.y);
        }
        int cnt = p1 - p; if (cnt > 16) cnt = 16;
        for (int j = 0; j < cnt; ++j) {
            int   r = __shfl(ev.x, wbase + j);
            float c = __shfl(cw,   wbase + j);
            float x0, x1, x2, x3;
            ld4bf(h1 + (size_t)r * HID + f, x0, x1, x2, x3);
            a0 += c * x0; a1 += c * x1; a2 += c * x2; a3 += c * x3;
        }
    }
    float x0, x1, x2, x3;
    ld4bf(h1 + (size_t)n * HID + f, x0, x1, x2, x3);
    float s = dn * dn;
    float4 o;
    o.x = fmaxf(dn * a0 + s * x0 + ldf(b1, f + 0, f32), 0.f);
    o.y = fmaxf(dn * a1 + s * x1 + ldf(b1, f + 1, f32), 0.f);
    o.z = fmaxf(dn * a2 + s * x2 + ldf(b1, f + 2, f32), 0.f);
    o.w = fmaxf(dn * a3 + s * x3 + ldf(b1, f + 3, f32), 0.f);
    *(float4*)(out1 + (size_t)n * HID + f) = o;
}

// ---- K7: h2 = out1 @ W2 ----
__global__ __launch_bounds__(256) void k_gemm2(const float* __restrict__ out1,
                                               const void* __restrict__ W2,
                                               const Flags* __restrict__ fl,
                                               float* __restrict__ h2) {
    __shared__ float Ws[HID * COUT];  // 4 KB
    int t = threadIdx.x;
    int f32 = fl->f32;
    for (int i = t; i < HID * COUT; i += 256) Ws[i] = ldf(W2, i, f32);
    __syncthreads();
    int node = blockIdx.x * 64 + (t >> 2);  // 64 nodes/block, 4 threads/node
    if (node >= NN) return;
    int o4 = (t & 3) * 4;
    const float* xr = out1 + (size_t)node * HID;
    float a0 = 0.f, a1 = 0.f, a2 = 0.f, a3 = 0.f;
#pragma unroll 4
    for (int k = 0; k < HID; ++k) {
        float xv = xr[k];
        const float* wr = &Ws[k * COUT + o4];
        a0 += xv * wr[0]; a1 += xv * wr[1]; a2 += xv * wr[2]; a3 += xv * wr[3];
    }
    float* ho = h2 + (size_t)node * COUT + o4;
    ho[0] = a0; ho[1] = a1; ho[2] = a2; ho[3] = a3;
}

// ---- K8: gather-aggregate layer 2, shfl-broadcast (4-lane groups) ----
__global__ __launch_bounds__(256) void k_agg2(const int* __restrict__ rowptrB,
                                              const int2* __restrict__ epack,
                                              const float* __restrict__ dinv2,
                                              const float* __restrict__ h2,
                                              const void* __restrict__ bias2,
                                              const Flags* __restrict__ fl,
                                              const int* __restrict__ delpos,
                                              void* __restrict__ out) {
    int t = threadIdx.x;
    int n = blockIdx.x * 64 + (t >> 2);  // 64 nodes/block, 4 lanes/node
    if (n >= NN) return;
    int l = t & 3;
    int f = l * 4;
    int wbase = t & 60;                  // group base lane within wave
    int f32 = fl->f32;
    int dp = *delpos;
    float dn = dinv2[n];
    int p0 = rowptrB[(size_t)n * NC], p1 = rowptrB[(size_t)(n + 1) * NC];
    float a0 = 0.f, a1 = 0.f, a2 = 0.f, a3 = 0.f;
    for (int p = p0; p < p1; p += 4) {
        int idx = p + l;
        int rr = 0;
        float cw = 0.f;
        if (idx < p1) {
            int2 ev = epack[idx];
            float w = (idx == dp) ? 0.f : __int_as_float(ev.y);
            rr = ev.x;
            cw = dinv2[rr] * w;
        }
        int cnt = p1 - p; if (cnt > 4) cnt = 4;
        for (int j = 0; j < cnt; ++j) {
            int   r = __shfl(rr, wbase + j);
            float c = __shfl(cw, wbase + j);
            const float4 hv = *(const float4*)(h2 + (size_t)r * COUT + f);
            a0 += c * hv.x; a1 += c * hv.y; a2 += c * hv.z; a3 += c * hv.w;
        }
    }
    float s = dn * dn;
    const float4 hn = *(const float4*)(h2 + (size_t)n * COUT + f);
    float o0 = dn * a0 + s * hn.x + ldf(bias2, f + 0, f32);
    float o1 = dn * a1 + s * hn.y + ldf(bias2, f + 1, f32);
    float o2 = dn * a2 + s * hn.z + ldf(bias2, f + 2, f32);
    float o3 = dn * a3 + s * hn.w + ldf(bias2, f + 3, f32);
    size_t idx = (size_t)n * COUT + f;
    if (f32) {
        float* op = (float*)out + idx;
        op[0] = o0; op[1] = o1; op[2] = o2; op[3] = o3;
    } else {
        union { uint2 u; __hip_bfloat16 h[4]; } pk;
        pk.h[0] = __float2bfloat16(o0); pk.h[1] = __float2bfloat16(o1);
        pk.h[2] = __float2bfloat16(o2); pk.h[3] = __float2bfloat16(o3);
        *(uint2*)((__hip_bfloat16*)out + idx) = pk.u;
    }
}

extern "C" void kernel_launch(void* const* d_in, const int* in_sizes, int n_in,
                              void* d_out, int out_size, void* d_ws, size_t ws_size,
                              hipStream_t stream) {
    const void* x  = d_in[0];
    const void* ei = d_in[1];
    const void* ew = d_in[2];
    const void* W1 = d_in[3];
    const void* b1 = d_in[4];
    const void* W2 = d_in[5];
    const void* b2 = d_in[6];

    // workspace layout: ~64.8 MB (h2 aliases hist8: hist8 dead after dinv/scanA,
    // h2 first written by k_gemm2 much later — safe on a single stream)
    char* wsb = (char*)d_ws;
    float* dinv1   = (float*)wsb;                      wsb += (size_t)NN * 4;
    float* dinv2   = (float*)wsb;                      wsb += (size_t)NN * 4;
    int*   rowptrB = (int*)wsb;                        wsb += (size_t)(NBINS + 1) * 4;
    int*   cursorB = (int*)wsb;                        wsb += (size_t)NBINS * 4;
    int*   blocksum= (int*)wsb;                        wsb += (size_t)SCAN_NB * 4;
    int*   blockoff= (int*)wsb;                        wsb += (size_t)SCAN_NB * 4;
    wsb = (char*)(((uintptr_t)wsb + 15) & ~(uintptr_t)15);
    u64*   hist8   = (u64*)wsb;                        // NBINS u64 = 6.4 MB ...
    float* h2      = (float*)wsb;                      wsb += (size_t)NBINS * 8;  // aliased
    int2*  epack   = (int2*)wsb;                       wsb += (size_t)NE * 8;
    __hip_bfloat16* h1 = (__hip_bfloat16*)wsb;         wsb += (size_t)NN * HID * 2;
    float* out1    = (float*)wsb;                      wsb += (size_t)NN * HID * 4;
    u64*   minkey  = (u64*)wsb;                        wsb += 8;
    Flags* fl      = (Flags*)wsb;                      wsb += 8;
    int*   delpos  = (int*)wsb;                        wsb += 8;

    hipMemsetAsync(hist8,   0, (size_t)NBINS * 8, stream);
    hipMemsetAsync(cursorB, 0, (size_t)NBINS * 4, stream);
    hipMemsetAsync(minkey, 0xFF, 8, stream);
    hipMemsetAsync(delpos, 0xFF, 4, stream);

    k_detect<<<1, 64, 0, stream>>>((const unsigned short*)x, (const int*)ei, fl);
    k_hist<<<(NE + 255) / 256, 256, 0, stream>>>(ei, ew, fl, hist8, minkey);
    k_dinv<<<(NN + 255) / 256, 256, 0, stream>>>(hist8, ei, ew, fl, minkey, dinv1, dinv2);
    k_scanA<<<SCAN_NB, SCAN_T, 0, stream>>>(hist8, rowptrB, blocksum);
    k_scanB<<<1, 1024, 0, stream>>>(blocksum, blockoff, rowptrB);
    k_scanC<<<SCAN_NB, SCAN_T, 0, stream>>>(blockoff, rowptrB);
    k_place<<<(NE + 255) / 256, 256, 0, stream>>>(ei, ew, fl, minkey, rowptrB, cursorB,
                                                  epack, delpos);
    k_gemm1_f32<<<(NN + 63) / 64, 256, 0, stream>>>((const float*)x, (const float*)W1,
                                                    fl, h1);
    k_gemm1_mfma<<<(NN / 16 + 15) / 16, 256, 0, stream>>>((const __hip_bfloat16*)x,
                                                          (const unsigned short*)W1, fl, h1);
    k_agg1<<<(NN + 15) / 16, 256, 0, stream>>>(rowptrB, epack, dinv1, h1, b1, fl, out1);
    k_gemm2<<<(NN + 63) / 64, 256, 0, stream>>>(out1, W2, fl, h2);
    k_agg2<<<(NN + 63) / 64, 256, 0, stream>>>(rowptrB, epack, dinv2, h2, b2, fl,
                                               delpos, d_out);
}